// Round 1
// baseline (307.608 us; speedup 1.0000x reference)
//
#include <hip/hip_runtime.h>
#include <hip/hip_bf16.h>

using bf16 = __hip_bfloat16;
typedef __bf16 bf16x8 __attribute__((ext_vector_type(8)));
typedef __bf16 bf16x4 __attribute__((ext_vector_type(4)));
typedef float f32x4 __attribute__((ext_vector_type(4)));

#define BK 64

// ---------------------------------------------------------------------------
// Staging helper: 16B per lane via global_load_lds, wave-uniform LDS base.
// ---------------------------------------------------------------------------
__device__ __forceinline__ void stage16(const bf16* gsrc, bf16* lds_base)
{
    __builtin_amdgcn_global_load_lds(
        (__attribute__((address_space(1))) void*)(void*)gsrc,
        (__attribute__((address_space(3))) void*)(void*)lds_base,
        16, 0, 0);
}

// LDS chunk swizzle: slot (row, c) holds global chunk (row, c^(row&7)).
// Kills the 16-way ds_read_b128 bank conflict (1.65e7 -> 0, measured R5).
// R8: 256x128 fc1 tile regressed (occupancy 28->16%); R9: 1-block/CU
// kernels are latency chains. R10: inline fp32*gw staging in the GEMM
// K-loop regressed. R11 (this round): fc1 moved to the 256^2 8-phase
// counted-vmcnt schedule (learn_hip m201 template) — the 128^2 2-barrier
// structure was stuck at ~670 TF (MfmaUtil 27%, HBM 16%: structure-bound).

// ---------------------------------------------------------------------------
// fc1: 256x256 tile, BK=64, 512 threads = 8 waves (2M x 4N), double-buffered
// 128 KiB LDS, 4 phases/K-tile, counted vmcnt(4) (never 0 in steady state).
// C = relu([A0|A1] @ [B0;B1]^T + bias), bf16 out.
//
// Phase schedule per K-tile u (quadrants (mh,nh)):
//   p0 (0,0): ds A[0]+B[0];      stage B[0] of u+1 -> buf^1
//   p1 (0,1): ds B[1];           stage B[1] of u+1 -> buf^1
//   p2 (1,1): ds A[1];           stage A[0] of u+2 -> buf   (A[0] retired p0)
//   p3 (1,0): (regs reused);     stage A[1] of u+2 -> buf   (A[1] retired p2)
//             s_waitcnt vmcnt(4)  -> retires exactly tile u+1's 4 units.
// Regions: A[h] = LDS rows {h*64..+63, 128+h*64..+63};
//          B[n] = rows with bit5==n. Each unit = 2 global_load_lds/thread.
// ---------------------------------------------------------------------------
__global__ __launch_bounds__(512)
void gemm_bt256(const bf16* __restrict__ A0, int lda0, int K0,
                const bf16* __restrict__ A1, int lda1, int K1,
                const bf16* __restrict__ B0, int ldb0,
                const bf16* __restrict__ B1, int ldb1,
                const float* __restrict__ bias,
                int relu,
                bf16* __restrict__ C, int ldc)
{
    __shared__ bf16 sA[2][256 * BK];
    __shared__ bf16 sB[2][256 * BK];

    const int t = threadIdx.x;
    const int w = t >> 6;          // wave 0..7
    const int l = t & 63;
    const int wm = w >> 2;         // 0..1  (128 rows each)
    const int wn = w & 3;          // 0..3  (64 cols each)
    const int r = l & 15;
    const int q = l >> 4;
    const int sw8 = r & 7;
    const int rowA0 = blockIdx.x * 256;
    const int rowB0 = blockIdx.y * 256;
    const int nK0 = K0 >> 6;
    const int nK = (K0 + K1) >> 6;

    f32x4 acc[8][4];
#pragma unroll
    for (int i = 0; i < 8; ++i)
#pragma unroll
        for (int j = 0; j < 4; ++j)
            acc[i][j] = (f32x4){0.f, 0.f, 0.f, 0.f};

    // ---- staging units (each: 2 x global_load_lds per thread) ----
    auto stageA = [&](int st, int bufsel, int h) {
        const bf16* P; int ld, ks;
        if (st < nK0) { P = A0; ld = lda0; ks = st << 6; }
        else          { P = A1; ld = lda1; ks = (st - nK0) << 6; }
#pragma unroll
        for (int s = 0; s < 2; ++s) {
            const int rr = t >> 3;                       // 0..63
            const int ldsrow = s * 128 + h * 64 + rr;
            const int cb = (t & 7) ^ (ldsrow & 7);
            stage16(P + (size_t)(rowA0 + ldsrow) * ld + ks + cb * 8,
                    &sA[bufsel][(s * 128 + h * 64 + (w << 3)) * BK]);
        }
    };
    auto stageB = [&](int st, int bufsel, int nh) {
        const bf16* P; int ld, ks;
        if (st < nK0) { P = B0; ld = ldb0; ks = st << 6; }
        else          { P = B1; ld = ldb1; ks = (st - nK0) << 6; }
#pragma unroll
        for (int s = 0; s < 2; ++s) {
            const int rr = t >> 3;                       // 0..63
            const int ldsrow = s * 128 + (rr >> 5) * 64 + nh * 32 + (rr & 31);
            const int cb = (t & 7) ^ (ldsrow & 7);
            stage16(P + (size_t)(rowB0 + ldsrow) * ld + ks + cb * 8,
                    &sB[bufsel][(s * 128 + (w >> 2) * 64 + nh * 32 + (w & 3) * 8) * BK]);
        }
    };

    // ---- fragment loads (swizzled ds_read_b128) ----
    bf16x8 aF[4][2], bF0[2][2], bF1[2][2];
    auto loadA = [&](int bufsel, int mh) {
#pragma unroll
        for (int i = 0; i < 4; ++i)
#pragma unroll
            for (int k = 0; k < 2; ++k)
                aF[i][k] = *(const bf16x8*)&sA[bufsel]
                    [(wm * 128 + mh * 64 + i * 16 + r) * BK + ((k * 4 + q) ^ sw8) * 8];
    };
    auto loadB0 = [&](int bufsel) {
#pragma unroll
        for (int j = 0; j < 2; ++j)
#pragma unroll
            for (int k = 0; k < 2; ++k)
                bF0[j][k] = *(const bf16x8*)&sB[bufsel]
                    [(wn * 64 + j * 16 + r) * BK + ((k * 4 + q) ^ sw8) * 8];
    };
    auto loadB1 = [&](int bufsel) {
#pragma unroll
        for (int j = 0; j < 2; ++j)
#pragma unroll
            for (int k = 0; k < 2; ++k)
                bF1[j][k] = *(const bf16x8*)&sB[bufsel]
                    [(wn * 64 + 32 + j * 16 + r) * BK + ((k * 4 + q) ^ sw8) * 8];
    };

    // ---- prologue: tile0 complete + tile1 A units in flight ----
    stageA(0, 0, 0); stageA(0, 0, 1);
    stageB(0, 0, 0); stageB(0, 0, 1);
    if (nK > 1) {
        stageA(1, 1, 0); stageA(1, 1, 1);
        asm volatile("s_waitcnt vmcnt(4)" ::: "memory");
    } else {
        asm volatile("s_waitcnt vmcnt(0)" ::: "memory");
    }
    __builtin_amdgcn_s_barrier();
    asm volatile("" ::: "memory");

    for (int u = 0; u < nK; ++u) {
        const int cb_ = u & 1;
        const int nb_ = cb_ ^ 1;

        // ---- p0: quadrant (0,0) ----
        loadA(cb_, 0);
        loadB0(cb_);
        if (u + 1 < nK) stageB(u + 1, nb_, 0);
        __builtin_amdgcn_s_barrier();
        asm volatile("s_waitcnt lgkmcnt(0)" ::: "memory");
        __builtin_amdgcn_sched_barrier(0);
        __builtin_amdgcn_s_setprio(1);
#pragma unroll
        for (int i = 0; i < 4; ++i)
#pragma unroll
            for (int j = 0; j < 2; ++j)
#pragma unroll
                for (int k = 0; k < 2; ++k)
                    acc[i][j] = __builtin_amdgcn_mfma_f32_16x16x32_bf16(
                        aF[i][k], bF0[j][k], acc[i][j], 0, 0, 0);
        __builtin_amdgcn_s_setprio(0);
        __builtin_amdgcn_s_barrier();
        asm volatile("" ::: "memory");

        // ---- p1: quadrant (0,1) ----
        loadB1(cb_);
        if (u + 1 < nK) stageB(u + 1, nb_, 1);
        __builtin_amdgcn_s_barrier();
        asm volatile("s_waitcnt lgkmcnt(0)" ::: "memory");
        __builtin_amdgcn_sched_barrier(0);
        __builtin_amdgcn_s_setprio(1);
#pragma unroll
        for (int i = 0; i < 4; ++i)
#pragma unroll
            for (int j = 0; j < 2; ++j)
#pragma unroll
                for (int k = 0; k < 2; ++k)
                    acc[i][2 + j] = __builtin_amdgcn_mfma_f32_16x16x32_bf16(
                        aF[i][k], bF1[j][k], acc[i][2 + j], 0, 0, 0);
        __builtin_amdgcn_s_setprio(0);
        __builtin_amdgcn_s_barrier();
        asm volatile("" ::: "memory");

        // ---- p2: quadrant (1,1) ----
        loadA(cb_, 1);
        if (u + 2 < nK) stageA(u + 2, cb_, 0);
        __builtin_amdgcn_s_barrier();
        asm volatile("s_waitcnt lgkmcnt(0)" ::: "memory");
        __builtin_amdgcn_sched_barrier(0);
        __builtin_amdgcn_s_setprio(1);
#pragma unroll
        for (int i = 0; i < 4; ++i)
#pragma unroll
            for (int j = 0; j < 2; ++j)
#pragma unroll
                for (int k = 0; k < 2; ++k)
                    acc[4 + i][2 + j] = __builtin_amdgcn_mfma_f32_16x16x32_bf16(
                        aF[i][k], bF1[j][k], acc[4 + i][2 + j], 0, 0, 0);
        __builtin_amdgcn_s_setprio(0);
        __builtin_amdgcn_s_barrier();
        asm volatile("" ::: "memory");

        // ---- p3: quadrant (1,0), counted vmcnt ----
        if (u + 2 < nK) stageA(u + 2, cb_, 1);
        if (u + 2 < nK) {
            asm volatile("s_waitcnt vmcnt(4)" ::: "memory");
        } else if (u + 1 < nK) {
            asm volatile("s_waitcnt vmcnt(0)" ::: "memory");
        }
        __builtin_amdgcn_s_barrier();
        __builtin_amdgcn_sched_barrier(0);
        __builtin_amdgcn_s_setprio(1);
#pragma unroll
        for (int i = 0; i < 4; ++i)
#pragma unroll
            for (int j = 0; j < 2; ++j)
#pragma unroll
                for (int k = 0; k < 2; ++k)
                    acc[4 + i][j] = __builtin_amdgcn_mfma_f32_16x16x32_bf16(
                        aF[i][k], bF0[j][k], acc[4 + i][j], 0, 0, 0);
        __builtin_amdgcn_s_setprio(0);
        __builtin_amdgcn_s_barrier();
        asm volatile("" ::: "memory");
    }

    // C/D layout: col = lane&15, row = quad*4 + reg (m89/m91 verified)
#pragma unroll
    for (int i = 0; i < 8; ++i)
#pragma unroll
        for (int j = 0; j < 4; ++j)
#pragma unroll
            for (int rr = 0; rr < 4; ++rr) {
                const int row = rowA0 + wm * 128 + i * 16 + q * 4 + rr;
                const int col = rowB0 + wn * 64 + j * 16 + r;
                float v = acc[i][j][rr];
                if (bias) v += bias[col];
                if (relu) v = v > 0.f ? v : 0.f;
                C[(size_t)row * ldc + col] = __float2bfloat16(v);
            }
}

// ---------------------------------------------------------------------------
// fc2: 64x128 tile, fp32 out. 768 balanced blocks.
// ---------------------------------------------------------------------------
__global__ __launch_bounds__(256)
void gemm_bt64(const bf16* __restrict__ A0, int lda0, int K0,
               const bf16* __restrict__ A1, int lda1, int K1,
               const bf16* __restrict__ B0, int ldb0,
               const bf16* __restrict__ B1, int ldb1,
               const float* __restrict__ bias,
               float* __restrict__ Cf, int ldc)
{
    __shared__ bf16 sA[64 * BK];
    __shared__ bf16 sB[128 * BK];

    const int t = threadIdx.x;
    const int w = t >> 6;
    const int l = t & 63;
    const int wn = w;
    const int r = l & 15;
    const int q = l >> 4;
    const int sw = r & 7;
    const int rowA0 = blockIdx.x * 64;
    const int rowB0 = blockIdx.y * 128;

    f32x4 acc[4][2];
#pragma unroll
    for (int i = 0; i < 4; ++i)
#pragma unroll
        for (int j = 0; j < 2; ++j)
            acc[i][j] = (f32x4){0.f, 0.f, 0.f, 0.f};

    const int nK = (K0 + K1) >> 6;
    for (int kt = 0; kt < nK; ++kt) {
        const int k0 = kt << 6;
        const bf16 *Ap, *Bp;
        int la, lb, ks;
        if (k0 < K0) { Ap = A0; la = lda0; Bp = B0; lb = ldb0; ks = k0; }
        else         { Ap = A1; la = lda1; Bp = B1; lb = ldb1; ks = k0 - K0; }

        __syncthreads();
#pragma unroll
        for (int it = 0; it < 2; ++it) {
            const int L   = it * 256 + t;
            const int row = L >> 3;
            const int cb  = (L & 7) ^ (row & 7);
            stage16(Ap + (size_t)(rowA0 + row) * la + ks + cb * 8,
                    sA + (size_t)(it * 256 + (w << 6)) * 8);
        }
#pragma unroll
        for (int it = 0; it < 4; ++it) {
            const int L   = it * 256 + t;
            const int row = L >> 3;
            const int cb  = (L & 7) ^ (row & 7);
            stage16(Bp + (size_t)(rowB0 + row) * lb + ks + cb * 8,
                    sB + (size_t)(it * 256 + (w << 6)) * 8);
        }
        __syncthreads();

#pragma unroll
        for (int kk = 0; kk < 2; ++kk) {
            const int ch = ((kk * 4 + q) ^ sw) * 8;
            bf16x8 aF[4], bF[2];
#pragma unroll
            for (int i = 0; i < 4; ++i)
                aF[i] = *(const bf16x8*)&sA[(i * 16 + r) * BK + ch];
#pragma unroll
            for (int j = 0; j < 2; ++j)
                bF[j] = *(const bf16x8*)&sB[(wn * 32 + j * 16 + r) * BK + ch];
#pragma unroll
            for (int i = 0; i < 4; ++i)
#pragma unroll
                for (int j = 0; j < 2; ++j)
                    acc[i][j] = __builtin_amdgcn_mfma_f32_16x16x32_bf16(
                        aF[i], bF[j], acc[i][j], 0, 0, 0);
        }
    }

#pragma unroll
    for (int i = 0; i < 4; ++i)
#pragma unroll
        for (int j = 0; j < 2; ++j)
#pragma unroll
            for (int rr = 0; rr < 4; ++rr) {
                const int row = rowA0 + i * 16 + q * 4 + rr;
                const int col = rowB0 + wn * 32 + j * 16 + r;
                Cf[(size_t)row * ldc + col] = acc[i][j][rr] + bias[col];
            }
}

// ---------------------------------------------------------------------------
// Fused router + t1 GEMM, 64-row tiles (384 blocks for TLP).
// B = [gate_w1 ; SVH1] contiguous [384,768]. Grid (128, 3), K=768 full.
//   y=0,1 (router): bias+relu+64-row sum -> atomicAdd gsum[16,256].
//   y=2   (t1):     raw fp32 x@SVH1^T -> t1acc (non-atomic).
// ---------------------------------------------------------------------------
__global__ __launch_bounds__(256)
void rt1_kernel(const bf16* __restrict__ A, int lda,
                const bf16* __restrict__ B, int ldb,
                const float* __restrict__ gate_b1,
                float* __restrict__ gsum, float* __restrict__ t1acc)
{
    __shared__ bf16 sA[64 * BK];
    __shared__ bf16 sB[128 * BK];

    const int t = threadIdx.x;
    const int w = t >> 6;
    const int l = t & 63;
    const int wn = w;
    const int r = l & 15;
    const int q = l >> 4;
    const int sw = r & 7;
    const int rowA0 = blockIdx.x * 64;
    const int rowB0 = blockIdx.y * 128;
    const int b = rowA0 >> 9;

    f32x4 acc[4][2];
#pragma unroll
    for (int i = 0; i < 4; ++i)
#pragma unroll
        for (int j = 0; j < 2; ++j)
            acc[i][j] = (f32x4){0.f, 0.f, 0.f, 0.f};

    for (int kt = 0; kt < 12; ++kt) {      // K = 768
        const int ks = kt << 6;

        __syncthreads();
#pragma unroll
        for (int it = 0; it < 2; ++it) {
            const int L   = it * 256 + t;
            const int row = L >> 3;
            const int cb  = (L & 7) ^ (row & 7);
            stage16(A + (size_t)(rowA0 + row) * lda + ks + cb * 8,
                    sA + (size_t)(it * 256 + (w << 6)) * 8);
        }
#pragma unroll
        for (int it = 0; it < 4; ++it) {
            const int L   = it * 256 + t;
            const int row = L >> 3;
            const int cb  = (L & 7) ^ (row & 7);
            stage16(B + (size_t)(rowB0 + row) * ldb + ks + cb * 8,
                    sB + (size_t)(it * 256 + (w << 6)) * 8);
        }
        __syncthreads();

#pragma unroll
        for (int kk = 0; kk < 2; ++kk) {
            const int ch = ((kk * 4 + q) ^ sw) * 8;
            bf16x8 aF[4], bF[2];
#pragma unroll
            for (int i = 0; i < 4; ++i)
                aF[i] = *(const bf16x8*)&sA[(i * 16 + r) * BK + ch];
#pragma unroll
            for (int j = 0; j < 2; ++j)
                bF[j] = *(const bf16x8*)&sB[(wn * 32 + j * 16 + r) * BK + ch];
#pragma unroll
            for (int i = 0; i < 4; ++i)
#pragma unroll
                for (int j = 0; j < 2; ++j)
                    acc[i][j] = __builtin_amdgcn_mfma_f32_16x16x32_bf16(
                        aF[i], bF[j], acc[i][j], 0, 0, 0);
        }
    }

    if (rowB0 < 256) {
#pragma unroll
        for (int j = 0; j < 2; ++j) {
            const int col = rowB0 + wn * 32 + j * 16 + r;
            const float bc = gate_b1[col];
            float s = 0.f;
#pragma unroll
            for (int i = 0; i < 4; ++i)
#pragma unroll
                for (int rr = 0; rr < 4; ++rr) {
                    const float v = acc[i][j][rr] + bc;
                    s += v > 0.f ? v : 0.f;
                }
            s += __shfl_xor(s, 16, 64);
            s += __shfl_xor(s, 32, 64);
            if (q == 0) atomicAdd(&gsum[b * 256 + col], s);
        }
    } else {
#pragma unroll
        for (int i = 0; i < 4; ++i)
#pragma unroll
            for (int j = 0; j < 2; ++j)
#pragma unroll
                for (int rr = 0; rr < 4; ++rr) {
                    const int row = rowA0 + i * 16 + q * 4 + rr;
                    const int col = wn * 32 + j * 16 + r;
                    t1acc[(size_t)row * 128 + col] = acc[i][j][rr];
                }
    }
}

// ---------------------------------------------------------------------------
// t2 split-K: grid (128, 1, 8), 64x128 tiles, 6 K-tiles per z, atomicAdd
// into pre-zeroed t2acc fp32. 1024 blocks = 4/CU for latency hiding.
// ---------------------------------------------------------------------------
__global__ __launch_bounds__(256)
void t2_splitk(const bf16* __restrict__ A, int lda,
               const bf16* __restrict__ B, int ldb,
               float* __restrict__ Cacc)
{
    __shared__ bf16 sA[64 * BK];
    __shared__ bf16 sB[128 * BK];

    const int t = threadIdx.x;
    const int w = t >> 6;
    const int l = t & 63;
    const int wn = w;
    const int r = l & 15;
    const int q = l >> 4;
    const int sw = r & 7;
    const int rowA0 = blockIdx.x * 64;
    const int ksbase = blockIdx.z * 6 * BK;

    f32x4 acc[4][2];
#pragma unroll
    for (int i = 0; i < 4; ++i)
#pragma unroll
        for (int j = 0; j < 2; ++j)
            acc[i][j] = (f32x4){0.f, 0.f, 0.f, 0.f};

    for (int kt = 0; kt < 6; ++kt) {
        const int ks = ksbase + kt * BK;

        __syncthreads();
#pragma unroll
        for (int it = 0; it < 2; ++it) {
            const int L   = it * 256 + t;
            const int row = L >> 3;
            const int cb  = (L & 7) ^ (row & 7);
            stage16(A + (size_t)(rowA0 + row) * lda + ks + cb * 8,
                    sA + (size_t)(it * 256 + (w << 6)) * 8);
        }
#pragma unroll
        for (int it = 0; it < 4; ++it) {
            const int L   = it * 256 + t;
            const int row = L >> 3;
            const int cb  = (L & 7) ^ (row & 7);
            stage16(B + (size_t)row * ldb + ks + cb * 8,
                    sB + (size_t)(it * 256 + (w << 6)) * 8);
        }
        __syncthreads();

#pragma unroll
        for (int kk = 0; kk < 2; ++kk) {
            const int ch = ((kk * 4 + q) ^ sw) * 8;
            bf16x8 aF[4], bF[2];
#pragma unroll
            for (int i = 0; i < 4; ++i)
                aF[i] = *(const bf16x8*)&sA[(i * 16 + r) * BK + ch];
#pragma unroll
            for (int j = 0; j < 2; ++j)
                bF[j] = *(const bf16x8*)&sB[(wn * 32 + j * 16 + r) * BK + ch];
#pragma unroll
            for (int i = 0; i < 4; ++i)
#pragma unroll
                for (int j = 0; j < 2; ++j)
                    acc[i][j] = __builtin_amdgcn_mfma_f32_16x16x32_bf16(
                        aF[i], bF[j], acc[i][j], 0, 0, 0);
        }
    }

#pragma unroll
    for (int i = 0; i < 4; ++i)
#pragma unroll
        for (int j = 0; j < 2; ++j)
#pragma unroll
            for (int rr = 0; rr < 4; ++rr) {
                const int row = rowA0 + i * 16 + q * 4 + rr;
                const int col = wn * 32 + j * 16 + r;
                atomicAdd(&Cacc[(size_t)row * 128 + col], acc[i][j][rr]);
            }
}

// t[i] = bf16(acc[i] * gw[batch(row)][col])   (M x 128)
__global__ void scale_cvt_kernel(const float* __restrict__ acc,
                                 const float* __restrict__ gw,
                                 bf16* __restrict__ outb)
{
    const int i = blockIdx.x * 256 + threadIdx.x;
    const int col = i & 127;
    const int row = i >> 7;
    outb[i] = __float2bfloat16(acc[i] * gw[(row >> 9) * 128 + col]);
}

// ---------------------------------------------------------------------------
// Fused prep: fp32->bf16 casts + coalesced LDS-tile U transposes + merged
// biases + zeroing of gsum and t2acc. One launch.
// ---------------------------------------------------------------------------
__device__ __forceinline__ void cvt_range(const float* src, bf16* dst, int base, int t)
{
    const int i = base * 256 + t;
    const float4 v = ((const float4*)src)[i];
    ((bf16x4*)dst)[i] = (bf16x4){(__bf16)v.x, (__bf16)v.y, (__bf16)v.z, (__bf16)v.w};
}

__device__ __forceinline__ void transpose_tile(const float* U, bf16* UT, int F,
                                               int bx, int by, int t,
                                               float (*sh)[65])
{
    const int f0 = bx * 64, ek0 = by * 64;
#pragma unroll
    for (int i = 0; i < 16; ++i) {
        const int row = i * 4 + (t >> 6);
        const int col = t & 63;
        sh[row][col] = U[(size_t)(ek0 + row) * F + f0 + col];
    }
    __syncthreads();
#pragma unroll
    for (int i = 0; i < 16; ++i) {
        const int row = i * 4 + (t >> 6);
        const int col = t & 63;
        UT[(size_t)(f0 + row) * 128 + ek0 + col] = __float2bfloat16(sh[col][row]);
    }
}

__global__ void prep_all(const float* __restrict__ x,    bf16* __restrict__ xb,
                         const float* __restrict__ W1,   bf16* __restrict__ W1b,
                         const float* __restrict__ W2,   bf16* __restrict__ W2b,
                         const float* __restrict__ gw1,  bf16* __restrict__ gw1b,
                         const float* __restrict__ gw2,  bf16* __restrict__ gw2b,
                         const float* __restrict__ SVH1, bf16* __restrict__ svh1b,
                         const float* __restrict__ SVH2, bf16* __restrict__ svh2b,
                         const float* __restrict__ U1,   bf16* __restrict__ U1T,
                         const float* __restrict__ U2,   bf16* __restrict__ U2T,
                         const float* __restrict__ b1,   const float* __restrict__ TB1,
                         const float* __restrict__ b2,   const float* __restrict__ TB2,
                         float* __restrict__ b1m, float* __restrict__ b2m,
                         float* __restrict__ gsum, float* __restrict__ t2acc)
{
    __shared__ float sh[64][65];
    const int b = blockIdx.x;
    const int t = threadIdx.x;
    if      (b < 6144)  cvt_range(x,   xb,   b,         t);
    else if (b < 8448)  cvt_range(W1,  W1b,  b - 6144,  t);
    else if (b < 10752) cvt_range(W2,  W2b,  b - 8448,  t);
    else if (b < 10944) cvt_range(gw1, gw1b, b - 10752, t);
    else if (b < 10976) cvt_range(gw2, gw2b, b - 10944, t);
    else if (b < 11072) cvt_range(SVH1, svh1b, b - 10976, t);
    else if (b < 11456) cvt_range(SVH2, svh2b, b - 11072, t);
    else if (b < 11552) {          // U1 [128,3072] -> U1T: 48 x 2 tiles
        const int b2 = b - 11456;
        transpose_tile(U1, U1T, 3072, b2 >> 1, b2 & 1, t, sh);
    } else if (b < 11576) {        // U2 [128,768] -> U2T: 12 x 2 tiles
        const int b2 = b - 11552;
        transpose_tile(U2, U2T, 768, b2 >> 1, b2 & 1, t, sh);
    } else if (b < 11591) {        // merged biases
        const int i = (b - 11576) * 256 + t;
        if (i < 3072) {
            float s = 0.f;
            for (int e = 0; e < 8; ++e) s += TB1[e * 3072 + i];
            b1m[i] = b1[i] + 0.2f * s;
        } else if (i < 3840) {
            const int j = i - 3072;
            float s = 0.f;
            for (int e = 0; e < 8; ++e) s += TB2[e * 768 + j];
            b2m[j] = b2[j] + 0.2f * s;
        }
    } else if (b < 11607) {        // zero gsum[4096]
        const int i = (b - 11591) * 256 + t;
        gsum[i] = 0.f;
    } else {                       // zero t2acc: 1M floats as float4
        const int i = (b - 11607) * 256 + t;
        ((float4*)t2acc)[i] = (float4){0.f, 0.f, 0.f, 0.f};
    }
}

// gw[b,c] = gate_b2[c] + (1/512) * sum_j gsum[b,j] * gate_w2[c,j]
__global__ void gw_kernel(const float* __restrict__ gsum, const bf16* __restrict__ gw2b,
                          const float* __restrict__ gate_b2, float* __restrict__ gw)
{
    const int b = blockIdx.x;
    const int c = threadIdx.x;
    float s = 0.f;
    for (int j = 0; j < 256; ++j)
        s += gsum[b * 256 + j] * __bfloat162float(gw2b[c * 256 + j]);
    gw[b * 128 + c] = gate_b2[c] + s * (1.0f / 512.0f);
}

// ---------------------------------------------------------------------------
extern "C" void kernel_launch(void* const* d_in, const int* in_sizes, int n_in,
                              void* d_out, int out_size, void* d_ws, size_t ws_size,
                              hipStream_t stream)
{
    const float* x       = (const float*)d_in[0];
    const float* gate_w1 = (const float*)d_in[1];
    const float* gate_b1 = (const float*)d_in[2];
    const float* gate_w2 = (const float*)d_in[3];
    const float* gate_b2 = (const float*)d_in[4];
    const float* W1      = (const float*)d_in[5];
    const float* b1      = (const float*)d_in[6];
    const float* W2      = (const float*)d_in[7];
    const float* b2      = (const float*)d_in[8];
    const float* U1      = (const float*)d_in[9];
    const float* SVH1    = (const float*)d_in[10];
    const float* U2      = (const float*)d_in[11];
    const float* SVH2    = (const float*)d_in[12];
    const float* TB1     = (const float*)d_in[13];
    const float* TB2     = (const float*)d_in[14];
    float* out = (float*)d_out;                     // [8192, 768] fp32

    char* p = (char*)d_ws;
    auto alloc = [&](size_t bytes) {
        char* q = p;
        p += (bytes + 255) & ~(size_t)255;
        return q;
    };
    bf16* hbuf  = (bf16*)alloc((size_t)8192 * 3072 * 2);
    bf16* xb    = (bf16*)alloc((size_t)8192 * 768 * 2);
    bf16* t1buf = (bf16*)alloc((size_t)8192 * 128 * 2);
    bf16* t2buf = (bf16*)alloc((size_t)8192 * 128 * 2);
    bf16* W1b   = (bf16*)alloc((size_t)3072 * 768 * 2);
    bf16* W2b   = (bf16*)alloc((size_t)768 * 3072 * 2);
    // gw1b and svh1b MUST be contiguous: rt1_kernel treats them as one
    // [384, 768] B matrix. 256*768*2 = 393216 B (multiple of 256 -> no pad).
    bf16* gw1b  = (bf16*)alloc((size_t)256 * 768 * 2);
    bf16* svh1b = (bf16*)alloc((size_t)128 * 768 * 2);
    bf16* gw2b  = (bf16*)alloc((size_t)128 * 256 * 2);
    bf16* svh2b = (bf16*)alloc((size_t)128 * 3072 * 2);
    bf16* U1T   = (bf16*)alloc((size_t)3072 * 128 * 2);
    bf16* U2T   = (bf16*)alloc((size_t)768 * 128 * 2);
    float* gsum = (float*)alloc(16 * 256 * 4);
    float* gw   = (float*)alloc(2048 * 4);
    float* b1m  = (float*)alloc(3072 * 4);
    float* b2m  = (float*)alloc(768 * 4);
    float* t1acc = (float*)alloc((size_t)8192 * 128 * 4);
    float* t2acc = (float*)alloc((size_t)8192 * 128 * 4);

    const dim3 blk(256);

    prep_all<<<12631, blk, 0, stream>>>(x, xb, W1, W1b, W2, W2b,
                                        gate_w1, gw1b, gate_w2, gw2b,
                                        SVH1, svh1b, SVH2, svh2b,
                                        U1, U1T, U2, U2T,
                                        b1, TB1, b2, TB2, b1m, b2m,
                                        gsum, t2acc);

    // fused router + t1raw (64-row tiles, 384 blocks)
    rt1_kernel<<<dim3(128, 3), blk, 0, stream>>>(xb, 768, gw1b, 768,
                                                 gate_b1, gsum, t1acc);
    // gw = gsum/512 @ gate_w2^T + gate_b2              [16, 128]
    gw_kernel<<<16, 128, 0, stream>>>(gsum, gw2b, gate_b2, gw);
    // t1 = t1acc * gw -> bf16
    scale_cvt_kernel<<<4096, blk, 0, stream>>>(t1acc, gw, t1buf);

    // h = relu([x|t1] @ [W1|U1T]^T + b1m)              [8192, 3072]
    // 256^2 8-phase counted-vmcnt kernel, 512 threads, grid (32,12)
    gemm_bt256<<<dim3(32, 12), dim3(512), 0, stream>>>(xb, 768, 768,
                                                       t1buf, 128, 128,
                                                       W1b, 768, U1T, 128,
                                                       b1m, 1, hbuf, 3072);

    // t2acc += h @ SVH2^T  (split-K z=8, 1024 blocks)  [8192, 128]
    t2_splitk<<<dim3(128, 1, 8), blk, 0, stream>>>(hbuf, 3072, svh2b, 3072, t2acc);
    // t2 = t2acc * gw -> bf16
    scale_cvt_kernel<<<4096, blk, 0, stream>>>(t2acc, gw, t2buf);

    // out = [h|t2] @ [W2|U2T]^T + b2m  (fp32 out)      [8192, 768]
    gemm_bt64<<<dim3(128, 6), blk, 0, stream>>>(hbuf, 3072, 3072, t2buf, 128, 128,
                                                W2b, 3072, U2T, 128,
                                                b2m, out, 768);
}

// Round 2
// 287.434 us; speedup vs baseline: 1.0702x; 1.0702x over previous
//
#include <hip/hip_runtime.h>
#include <hip/hip_bf16.h>

using bf16 = __hip_bfloat16;
typedef __bf16 bf16x8 __attribute__((ext_vector_type(8)));
typedef __bf16 bf16x4 __attribute__((ext_vector_type(4)));
typedef float f32x4 __attribute__((ext_vector_type(4)));
typedef float f32x16 __attribute__((ext_vector_type(16)));

#define BK 64

// ---------------------------------------------------------------------------
// Staging helper: 16B per lane via global_load_lds, wave-uniform LDS base.
// ---------------------------------------------------------------------------
__device__ __forceinline__ void stage16(const bf16* gsrc, bf16* lds_base)
{
    __builtin_amdgcn_global_load_lds(
        (__attribute__((address_space(1))) void*)(void*)gsrc,
        (__attribute__((address_space(3))) void*)(void*)lds_base,
        16, 0, 0);
}

// LDS chunk swizzle: slot (row, c) holds global chunk (row, c^(row&7)).
// Kills the 16-way ds_read_b128 bank conflict (1.65e7 -> 0, measured R5).
// R8: 256x128 fc1 tile regressed (occupancy 28->16%); R9: 1-block/CU
// kernels are latency chains. R10: inline fp32*gw staging regressed.
// R11: 256^2 8-phase counted-vmcnt schedule REGRESSED here (67->97us):
//   384 blocks @ 1 block/CU = 1.5 grid rounds (half machine idle in round
//   2) + K=896 is only 14 K-tiles so the deep pipeline never amortizes.
//   8-phase is a long-K / exact-grid technique — wrong regime for this op.
// R12 (this round): hot loops moved to mfma_f32_32x32x16_bf16 — 2x FLOP
//   per instruction (halves MFMA count), ~25% more FLOP/cyc at the pipe
//   (m119: 2495 vs 2176 TF), same LDS layout/swizzle/traffic.
// ---------------------------------------------------------------------------

// ---------------------------------------------------------------------------
// fc1: 128x128 tiled MFMA GEMM, 32x32x16 fragments.
// C = relu([A0|A1] @ [B0;B1]^T + bias), bf16 out. Block=256 (4 waves, 2x2,
// each wave 64x64 = 2x2 fragments of 32x32).
// A-frag layout (doubling analog of verified 16x16x32): lane l holds
// A[row=l&31][k=(l>>5)*8+j]; B symmetric. C/D: col=lane&31,
// row=(reg&3)+8*(reg>>2)+4*(lane>>5)  [m74/m101 verified].
// ---------------------------------------------------------------------------
__global__ __launch_bounds__(256)
void gemm_bt(const bf16* __restrict__ A0, int lda0, int K0,
             const bf16* __restrict__ A1, int lda1, int K1,
             const bf16* __restrict__ B0, int ldb0,
             const bf16* __restrict__ B1, int ldb1,
             const float* __restrict__ bias,
             int relu,
             bf16* __restrict__ C, int ldc)
{
    __shared__ bf16 sA[128 * BK];
    __shared__ bf16 sB[128 * BK];

    const int t = threadIdx.x;
    const int w = t >> 6;
    const int l = t & 63;
    const int wm = w >> 1;
    const int wn = w & 1;
    const int r32 = l & 31;        // row within 32x32 fragment
    const int h   = l >> 5;        // k-half selector
    const int rowA0 = blockIdx.x * 128;
    const int rowB0 = blockIdx.y * 128;

    f32x16 acc[2][2];
#pragma unroll
    for (int i = 0; i < 2; ++i)
#pragma unroll
        for (int j = 0; j < 2; ++j)
#pragma unroll
            for (int e = 0; e < 16; ++e)
                acc[i][j][e] = 0.f;

    const int nK = (K0 + K1) >> 6;
    for (int kt = 0; kt < nK; ++kt) {
        const int k0 = kt << 6;
        const bf16 *Ap, *Bp;
        int la, lb, ks;
        if (k0 < K0) { Ap = A0; la = lda0; Bp = B0; lb = ldb0; ks = k0; }
        else         { Ap = A1; la = lda1; Bp = B1; lb = ldb1; ks = k0 - K0; }

        __syncthreads();
#pragma unroll
        for (int it = 0; it < 4; ++it) {
            const int L   = it * 256 + t;
            const int row = L >> 3;
            const int cb  = (L & 7) ^ (row & 7);   // swizzled source chunk
            stage16(Ap + (size_t)(rowA0 + row) * la + ks + cb * 8,
                    sA + (size_t)(it * 256 + (w << 6)) * 8);
            stage16(Bp + (size_t)(rowB0 + row) * lb + ks + cb * 8,
                    sB + (size_t)(it * 256 + (w << 6)) * 8);
        }
        __syncthreads();

#pragma unroll
        for (int s = 0; s < 4; ++s) {              // 4 x K=16 sub-steps
            bf16x8 aF[2], bF[2];
#pragma unroll
            for (int i = 0; i < 2; ++i) {
                const int row = wm * 64 + i * 32 + r32;
                const int c   = (s * 2 + h) ^ (row & 7);
                aF[i] = *(const bf16x8*)&sA[row * BK + c * 8];
            }
#pragma unroll
            for (int j = 0; j < 2; ++j) {
                const int row = wn * 64 + j * 32 + r32;
                const int c   = (s * 2 + h) ^ (row & 7);
                bF[j] = *(const bf16x8*)&sB[row * BK + c * 8];
            }
#pragma unroll
            for (int i = 0; i < 2; ++i)
#pragma unroll
                for (int j = 0; j < 2; ++j)
                    acc[i][j] = __builtin_amdgcn_mfma_f32_32x32x16_bf16(
                        aF[i], bF[j], acc[i][j], 0, 0, 0);
        }
    }

    // C/D layout: col = lane&31, row = (reg&3) + 8*(reg>>2) + 4*h
#pragma unroll
    for (int i = 0; i < 2; ++i)
#pragma unroll
        for (int j = 0; j < 2; ++j) {
            const int col = rowB0 + wn * 64 + j * 32 + r32;
            const float bc = bias ? bias[col] : 0.f;
#pragma unroll
            for (int reg = 0; reg < 16; ++reg) {
                const int row = rowA0 + wm * 64 + i * 32 +
                                (reg & 3) + 8 * (reg >> 2) + 4 * h;
                float v = acc[i][j][reg] + bc;
                if (relu) v = v > 0.f ? v : 0.f;
                C[(size_t)row * ldc + col] = __float2bfloat16(v);
            }
        }
}

// ---------------------------------------------------------------------------
// fc2: 64x128 tile, fp32 out, 32x32x16 fragments. 768 balanced blocks.
// 4 waves 1x4; each wave 64x32 = 2x1 fragments of 32x32.
// ---------------------------------------------------------------------------
__global__ __launch_bounds__(256)
void gemm_bt64(const bf16* __restrict__ A0, int lda0, int K0,
               const bf16* __restrict__ A1, int lda1, int K1,
               const bf16* __restrict__ B0, int ldb0,
               const bf16* __restrict__ B1, int ldb1,
               const float* __restrict__ bias,
               float* __restrict__ Cf, int ldc)
{
    __shared__ bf16 sA[64 * BK];
    __shared__ bf16 sB[128 * BK];

    const int t = threadIdx.x;
    const int w = t >> 6;
    const int l = t & 63;
    const int wn = w;
    const int r32 = l & 31;
    const int h   = l >> 5;
    const int rowA0 = blockIdx.x * 64;
    const int rowB0 = blockIdx.y * 128;

    f32x16 acc[2];
#pragma unroll
    for (int i = 0; i < 2; ++i)
#pragma unroll
        for (int e = 0; e < 16; ++e)
            acc[i][e] = 0.f;

    const int nK = (K0 + K1) >> 6;
    for (int kt = 0; kt < nK; ++kt) {
        const int k0 = kt << 6;
        const bf16 *Ap, *Bp;
        int la, lb, ks;
        if (k0 < K0) { Ap = A0; la = lda0; Bp = B0; lb = ldb0; ks = k0; }
        else         { Ap = A1; la = lda1; Bp = B1; lb = ldb1; ks = k0 - K0; }

        __syncthreads();
#pragma unroll
        for (int it = 0; it < 2; ++it) {
            const int L   = it * 256 + t;
            const int row = L >> 3;
            const int cb  = (L & 7) ^ (row & 7);
            stage16(Ap + (size_t)(rowA0 + row) * la + ks + cb * 8,
                    sA + (size_t)(it * 256 + (w << 6)) * 8);
        }
#pragma unroll
        for (int it = 0; it < 4; ++it) {
            const int L   = it * 256 + t;
            const int row = L >> 3;
            const int cb  = (L & 7) ^ (row & 7);
            stage16(Bp + (size_t)(rowB0 + row) * lb + ks + cb * 8,
                    sB + (size_t)(it * 256 + (w << 6)) * 8);
        }
        __syncthreads();

#pragma unroll
        for (int s = 0; s < 4; ++s) {
            bf16x8 aF[2], bF;
#pragma unroll
            for (int i = 0; i < 2; ++i) {
                const int row = i * 32 + r32;
                const int c   = (s * 2 + h) ^ (row & 7);
                aF[i] = *(const bf16x8*)&sA[row * BK + c * 8];
            }
            {
                const int row = wn * 32 + r32;
                const int c   = (s * 2 + h) ^ (row & 7);
                bF = *(const bf16x8*)&sB[row * BK + c * 8];
            }
#pragma unroll
            for (int i = 0; i < 2; ++i)
                acc[i] = __builtin_amdgcn_mfma_f32_32x32x16_bf16(
                    aF[i], bF, acc[i], 0, 0, 0);
        }
    }

#pragma unroll
    for (int i = 0; i < 2; ++i) {
        const int col = rowB0 + wn * 32 + r32;
        const float bc = bias[col];
#pragma unroll
        for (int reg = 0; reg < 16; ++reg) {
            const int row = rowA0 + i * 32 + (reg & 3) + 8 * (reg >> 2) + 4 * h;
            Cf[(size_t)row * ldc + col] = acc[i][reg] + bc;
        }
    }
}

// ---------------------------------------------------------------------------
// Fused router + t1 GEMM, 64-row tiles (384 blocks for TLP).
// B = [gate_w1 ; SVH1] contiguous [384,768]. Grid (128, 3), K=768 full.
//   y=0,1 (router): bias+relu+64-row sum -> atomicAdd gsum[16,256].
//   y=2   (t1):     raw fp32 x@SVH1^T -> t1acc (non-atomic).
// ---------------------------------------------------------------------------
__global__ __launch_bounds__(256)
void rt1_kernel(const bf16* __restrict__ A, int lda,
                const bf16* __restrict__ B, int ldb,
                const float* __restrict__ gate_b1,
                float* __restrict__ gsum, float* __restrict__ t1acc)
{
    __shared__ bf16 sA[64 * BK];
    __shared__ bf16 sB[128 * BK];

    const int t = threadIdx.x;
    const int w = t >> 6;
    const int l = t & 63;
    const int wn = w;
    const int r = l & 15;
    const int q = l >> 4;
    const int sw = r & 7;
    const int rowA0 = blockIdx.x * 64;
    const int rowB0 = blockIdx.y * 128;
    const int b = rowA0 >> 9;

    f32x4 acc[4][2];
#pragma unroll
    for (int i = 0; i < 4; ++i)
#pragma unroll
        for (int j = 0; j < 2; ++j)
            acc[i][j] = (f32x4){0.f, 0.f, 0.f, 0.f};

    for (int kt = 0; kt < 12; ++kt) {      // K = 768
        const int ks = kt << 6;

        __syncthreads();
#pragma unroll
        for (int it = 0; it < 2; ++it) {
            const int L   = it * 256 + t;
            const int row = L >> 3;
            const int cb  = (L & 7) ^ (row & 7);
            stage16(A + (size_t)(rowA0 + row) * lda + ks + cb * 8,
                    sA + (size_t)(it * 256 + (w << 6)) * 8);
        }
#pragma unroll
        for (int it = 0; it < 4; ++it) {
            const int L   = it * 256 + t;
            const int row = L >> 3;
            const int cb  = (L & 7) ^ (row & 7);
            stage16(B + (size_t)(rowB0 + row) * ldb + ks + cb * 8,
                    sB + (size_t)(it * 256 + (w << 6)) * 8);
        }
        __syncthreads();

#pragma unroll
        for (int kk = 0; kk < 2; ++kk) {
            const int ch = ((kk * 4 + q) ^ sw) * 8;
            bf16x8 aF[4], bF[2];
#pragma unroll
            for (int i = 0; i < 4; ++i)
                aF[i] = *(const bf16x8*)&sA[(i * 16 + r) * BK + ch];
#pragma unroll
            for (int j = 0; j < 2; ++j)
                bF[j] = *(const bf16x8*)&sB[(wn * 32 + j * 16 + r) * BK + ch];
#pragma unroll
            for (int i = 0; i < 4; ++i)
#pragma unroll
                for (int j = 0; j < 2; ++j)
                    acc[i][j] = __builtin_amdgcn_mfma_f32_16x16x32_bf16(
                        aF[i], bF[j], acc[i][j], 0, 0, 0);
        }
    }

    if (rowB0 < 256) {
#pragma unroll
        for (int j = 0; j < 2; ++j) {
            const int col = rowB0 + wn * 32 + j * 16 + r;
            const float bc = gate_b1[col];
            float s = 0.f;
#pragma unroll
            for (int i = 0; i < 4; ++i)
#pragma unroll
                for (int rr = 0; rr < 4; ++rr) {
                    const float v = acc[i][j][rr] + bc;
                    s += v > 0.f ? v : 0.f;
                }
            s += __shfl_xor(s, 16, 64);
            s += __shfl_xor(s, 32, 64);
            if (q == 0) atomicAdd(&gsum[b * 256 + col], s);
        }
    } else {
#pragma unroll
        for (int i = 0; i < 4; ++i)
#pragma unroll
            for (int j = 0; j < 2; ++j)
#pragma unroll
                for (int rr = 0; rr < 4; ++rr) {
                    const int row = rowA0 + i * 16 + q * 4 + rr;
                    const int col = wn * 32 + j * 16 + r;
                    t1acc[(size_t)row * 128 + col] = acc[i][j][rr];
                }
    }
}

// ---------------------------------------------------------------------------
// t2 split-K: grid (128, 1, 8), 64x128 tiles, 6 K-tiles per z, atomicAdd
// into pre-zeroed t2acc fp32. 1024 blocks = 4/CU for latency hiding.
// ---------------------------------------------------------------------------
__global__ __launch_bounds__(256)
void t2_splitk(const bf16* __restrict__ A, int lda,
               const bf16* __restrict__ B, int ldb,
               float* __restrict__ Cacc)
{
    __shared__ bf16 sA[64 * BK];
    __shared__ bf16 sB[128 * BK];

    const int t = threadIdx.x;
    const int w = t >> 6;
    const int l = t & 63;
    const int wn = w;
    const int r = l & 15;
    const int q = l >> 4;
    const int sw = r & 7;
    const int rowA0 = blockIdx.x * 64;
    const int ksbase = blockIdx.z * 6 * BK;

    f32x4 acc[4][2];
#pragma unroll
    for (int i = 0; i < 4; ++i)
#pragma unroll
        for (int j = 0; j < 2; ++j)
            acc[i][j] = (f32x4){0.f, 0.f, 0.f, 0.f};

    for (int kt = 0; kt < 6; ++kt) {
        const int ks = ksbase + kt * BK;

        __syncthreads();
#pragma unroll
        for (int it = 0; it < 2; ++it) {
            const int L   = it * 256 + t;
            const int row = L >> 3;
            const int cb  = (L & 7) ^ (row & 7);
            stage16(A + (size_t)(rowA0 + row) * lda + ks + cb * 8,
                    sA + (size_t)(it * 256 + (w << 6)) * 8);
        }
#pragma unroll
        for (int it = 0; it < 4; ++it) {
            const int L   = it * 256 + t;
            const int row = L >> 3;
            const int cb  = (L & 7) ^ (row & 7);
            stage16(B + (size_t)row * ldb + ks + cb * 8,
                    sB + (size_t)(it * 256 + (w << 6)) * 8);
        }
        __syncthreads();

#pragma unroll
        for (int kk = 0; kk < 2; ++kk) {
            const int ch = ((kk * 4 + q) ^ sw) * 8;
            bf16x8 aF[4], bF[2];
#pragma unroll
            for (int i = 0; i < 4; ++i)
                aF[i] = *(const bf16x8*)&sA[(i * 16 + r) * BK + ch];
#pragma unroll
            for (int j = 0; j < 2; ++j)
                bF[j] = *(const bf16x8*)&sB[(wn * 32 + j * 16 + r) * BK + ch];
#pragma unroll
            for (int i = 0; i < 4; ++i)
#pragma unroll
                for (int j = 0; j < 2; ++j)
                    acc[i][j] = __builtin_amdgcn_mfma_f32_16x16x32_bf16(
                        aF[i], bF[j], acc[i][j], 0, 0, 0);
        }
    }

#pragma unroll
    for (int i = 0; i < 4; ++i)
#pragma unroll
        for (int j = 0; j < 2; ++j)
#pragma unroll
            for (int rr = 0; rr < 4; ++rr) {
                const int row = rowA0 + i * 16 + q * 4 + rr;
                const int col = wn * 32 + j * 16 + r;
                atomicAdd(&Cacc[(size_t)row * 128 + col], acc[i][j][rr]);
            }
}

// t[i] = bf16(acc[i] * gw[batch(row)][col])   (M x 128)
__global__ void scale_cvt_kernel(const float* __restrict__ acc,
                                 const float* __restrict__ gw,
                                 bf16* __restrict__ outb)
{
    const int i = blockIdx.x * 256 + threadIdx.x;
    const int col = i & 127;
    const int row = i >> 7;
    outb[i] = __float2bfloat16(acc[i] * gw[(row >> 9) * 128 + col]);
}

// ---------------------------------------------------------------------------
// Fused prep: fp32->bf16 casts + coalesced LDS-tile U transposes + merged
// biases + zeroing of gsum and t2acc. One launch.
// ---------------------------------------------------------------------------
__device__ __forceinline__ void cvt_range(const float* src, bf16* dst, int base, int t)
{
    const int i = base * 256 + t;
    const float4 v = ((const float4*)src)[i];
    ((bf16x4*)dst)[i] = (bf16x4){(__bf16)v.x, (__bf16)v.y, (__bf16)v.z, (__bf16)v.w};
}

__device__ __forceinline__ void transpose_tile(const float* U, bf16* UT, int F,
                                               int bx, int by, int t,
                                               float (*sh)[65])
{
    const int f0 = bx * 64, ek0 = by * 64;
#pragma unroll
    for (int i = 0; i < 16; ++i) {
        const int row = i * 4 + (t >> 6);
        const int col = t & 63;
        sh[row][col] = U[(size_t)(ek0 + row) * F + f0 + col];
    }
    __syncthreads();
#pragma unroll
    for (int i = 0; i < 16; ++i) {
        const int row = i * 4 + (t >> 6);
        const int col = t & 63;
        UT[(size_t)(f0 + row) * 128 + ek0 + col] = __float2bfloat16(sh[col][row]);
    }
}

__global__ void prep_all(const float* __restrict__ x,    bf16* __restrict__ xb,
                         const float* __restrict__ W1,   bf16* __restrict__ W1b,
                         const float* __restrict__ W2,   bf16* __restrict__ W2b,
                         const float* __restrict__ gw1,  bf16* __restrict__ gw1b,
                         const float* __restrict__ gw2,  bf16* __restrict__ gw2b,
                         const float* __restrict__ SVH1, bf16* __restrict__ svh1b,
                         const float* __restrict__ SVH2, bf16* __restrict__ svh2b,
                         const float* __restrict__ U1,   bf16* __restrict__ U1T,
                         const float* __restrict__ U2,   bf16* __restrict__ U2T,
                         const float* __restrict__ b1,   const float* __restrict__ TB1,
                         const float* __restrict__ b2,   const float* __restrict__ TB2,
                         float* __restrict__ b1m, float* __restrict__ b2m,
                         float* __restrict__ gsum, float* __restrict__ t2acc)
{
    __shared__ float sh[64][65];
    const int b = blockIdx.x;
    const int t = threadIdx.x;
    if      (b < 6144)  cvt_range(x,   xb,   b,         t);
    else if (b < 8448)  cvt_range(W1,  W1b,  b - 6144,  t);
    else if (b < 10752) cvt_range(W2,  W2b,  b - 8448,  t);
    else if (b < 10944) cvt_range(gw1, gw1b, b - 10752, t);
    else if (b < 10976) cvt_range(gw2, gw2b, b - 10944, t);
    else if (b < 11072) cvt_range(SVH1, svh1b, b - 10976, t);
    else if (b < 11456) cvt_range(SVH2, svh2b, b - 11072, t);
    else if (b < 11552) {          // U1 [128,3072] -> U1T: 48 x 2 tiles
        const int b2 = b - 11456;
        transpose_tile(U1, U1T, 3072, b2 >> 1, b2 & 1, t, sh);
    } else if (b < 11576) {        // U2 [128,768] -> U2T: 12 x 2 tiles
        const int b2 = b - 11552;
        transpose_tile(U2, U2T, 768, b2 >> 1, b2 & 1, t, sh);
    } else if (b < 11591) {        // merged biases
        const int i = (b - 11576) * 256 + t;
        if (i < 3072) {
            float s = 0.f;
            for (int e = 0; e < 8; ++e) s += TB1[e * 3072 + i];
            b1m[i] = b1[i] + 0.2f * s;
        } else if (i < 3840) {
            const int j = i - 3072;
            float s = 0.f;
            for (int e = 0; e < 8; ++e) s += TB2[e * 768 + j];
            b2m[j] = b2[j] + 0.2f * s;
        }
    } else if (b < 11607) {        // zero gsum[4096]
        const int i = (b - 11591) * 256 + t;
        gsum[i] = 0.f;
    } else {                       // zero t2acc: 1M floats as float4
        const int i = (b - 11607) * 256 + t;
        ((float4*)t2acc)[i] = (float4){0.f, 0.f, 0.f, 0.f};
    }
}

// gw[b,c] = gate_b2[c] + (1/512) * sum_j gsum[b,j] * gate_w2[c,j]
__global__ void gw_kernel(const float* __restrict__ gsum, const bf16* __restrict__ gw2b,
                          const float* __restrict__ gate_b2, float* __restrict__ gw)
{
    const int b = blockIdx.x;
    const int c = threadIdx.x;
    float s = 0.f;
    for (int j = 0; j < 256; ++j)
        s += gsum[b * 256 + j] * __bfloat162float(gw2b[c * 256 + j]);
    gw[b * 128 + c] = gate_b2[c] + s * (1.0f / 512.0f);
}

// ---------------------------------------------------------------------------
extern "C" void kernel_launch(void* const* d_in, const int* in_sizes, int n_in,
                              void* d_out, int out_size, void* d_ws, size_t ws_size,
                              hipStream_t stream)
{
    const float* x       = (const float*)d_in[0];
    const float* gate_w1 = (const float*)d_in[1];
    const float* gate_b1 = (const float*)d_in[2];
    const float* gate_w2 = (const float*)d_in[3];
    const float* gate_b2 = (const float*)d_in[4];
    const float* W1      = (const float*)d_in[5];
    const float* b1      = (const float*)d_in[6];
    const float* W2      = (const float*)d_in[7];
    const float* b2      = (const float*)d_in[8];
    const float* U1      = (const float*)d_in[9];
    const float* SVH1    = (const float*)d_in[10];
    const float* U2      = (const float*)d_in[11];
    const float* SVH2    = (const float*)d_in[12];
    const float* TB1     = (const float*)d_in[13];
    const float* TB2     = (const float*)d_in[14];
    float* out = (float*)d_out;                     // [8192, 768] fp32

    char* p = (char*)d_ws;
    auto alloc = [&](size_t bytes) {
        char* q = p;
        p += (bytes + 255) & ~(size_t)255;
        return q;
    };
    bf16* hbuf  = (bf16*)alloc((size_t)8192 * 3072 * 2);
    bf16* xb    = (bf16*)alloc((size_t)8192 * 768 * 2);
    bf16* t1buf = (bf16*)alloc((size_t)8192 * 128 * 2);
    bf16* t2buf = (bf16*)alloc((size_t)8192 * 128 * 2);
    bf16* W1b   = (bf16*)alloc((size_t)3072 * 768 * 2);
    bf16* W2b   = (bf16*)alloc((size_t)768 * 3072 * 2);
    // gw1b and svh1b MUST be contiguous: rt1_kernel treats them as one
    // [384, 768] B matrix. 256*768*2 = 393216 B (multiple of 256 -> no pad).
    bf16* gw1b  = (bf16*)alloc((size_t)256 * 768 * 2);
    bf16* svh1b = (bf16*)alloc((size_t)128 * 768 * 2);
    bf16* gw2b  = (bf16*)alloc((size_t)128 * 256 * 2);
    bf16* svh2b = (bf16*)alloc((size_t)128 * 3072 * 2);
    bf16* U1T   = (bf16*)alloc((size_t)3072 * 128 * 2);
    bf16* U2T   = (bf16*)alloc((size_t)768 * 128 * 2);
    float* gsum = (float*)alloc(16 * 256 * 4);
    float* gw   = (float*)alloc(2048 * 4);
    float* b1m  = (float*)alloc(3072 * 4);
    float* b2m  = (float*)alloc(768 * 4);
    float* t1acc = (float*)alloc((size_t)8192 * 128 * 4);
    float* t2acc = (float*)alloc((size_t)8192 * 128 * 4);

    const dim3 blk(256);

    prep_all<<<12631, blk, 0, stream>>>(x, xb, W1, W1b, W2, W2b,
                                        gate_w1, gw1b, gate_w2, gw2b,
                                        SVH1, svh1b, SVH2, svh2b,
                                        U1, U1T, U2, U2T,
                                        b1, TB1, b2, TB2, b1m, b2m,
                                        gsum, t2acc);

    // fused router + t1raw (64-row tiles, 384 blocks)
    rt1_kernel<<<dim3(128, 3), blk, 0, stream>>>(xb, 768, gw1b, 768,
                                                 gate_b1, gsum, t1acc);
    // gw = gsum/512 @ gate_w2^T + gate_b2              [16, 128]
    gw_kernel<<<16, 128, 0, stream>>>(gsum, gw2b, gate_b2, gw);
    // t1 = t1acc * gw -> bf16
    scale_cvt_kernel<<<4096, blk, 0, stream>>>(t1acc, gw, t1buf);

    // h = relu([x|t1] @ [W1|U1T]^T + b1m)              [8192, 3072]
    gemm_bt<<<dim3(64, 24), blk, 0, stream>>>(xb, 768, 768, t1buf, 128, 128,
                                              W1b, 768, U1T, 128,
                                              b1m, 1, hbuf, 3072);

    // t2acc += h @ SVH2^T  (split-K z=8, 1024 blocks)  [8192, 128]
    t2_splitk<<<dim3(128, 1, 8), blk, 0, stream>>>(hbuf, 3072, svh2b, 3072, t2acc);
    // t2 = t2acc * gw -> bf16
    scale_cvt_kernel<<<4096, blk, 0, stream>>>(t2acc, gw, t2buf);

    // out = [h|t2] @ [W2|U2T]^T + b2m  (fp32 out)      [8192, 768]
    gemm_bt64<<<dim3(128, 6), blk, 0, stream>>>(hbuf, 3072, 3072, t2buf, 128, 128,
                                                W2b, 3072, U2T, 128,
                                                b2m, out, 768);
}

// Round 3
// 281.607 us; speedup vs baseline: 1.0923x; 1.0207x over previous
//
#include <hip/hip_runtime.h>
#include <hip/hip_bf16.h>

using bf16 = __hip_bfloat16;
typedef __bf16 bf16x8 __attribute__((ext_vector_type(8)));
typedef __bf16 bf16x4 __attribute__((ext_vector_type(4)));
typedef float f32x4 __attribute__((ext_vector_type(4)));
typedef float f32x16 __attribute__((ext_vector_type(16)));

#define BK 64

// ---------------------------------------------------------------------------
// Staging helper: 16B per lane via global_load_lds, wave-uniform LDS base.
// ---------------------------------------------------------------------------
__device__ __forceinline__ void stage16(const bf16* gsrc, bf16* lds_base)
{
    __builtin_amdgcn_global_load_lds(
        (__attribute__((address_space(1))) void*)(void*)gsrc,
        (__attribute__((address_space(3))) void*)(void*)lds_base,
        16, 0, 0);
}

// LDS chunk swizzle history:
// R5: slot (row,c) holds chunk c^(row&7) — killed 16-way conflict for the
//     16x16 read pattern (1.65e7 -> 0).
// R11: 256^2 8-phase schedule regressed (grid quantization + short K).
// R12: 32x32x16 MFMA halved instruction count (fc1 67->62.6us) BUT
//     reintroduced conflicts: 5.5e6 = exactly 4 cyc/ds_read_b128. Cause:
//     lanes (l, l+16) read row r / r+16 with the SAME chunk slot
//     ((r+16)&7 == r&7) -> same bank-quad, distinct address. The 16x16
//     pattern has those pairs on different chunks (q in the constant).
// R13 (this round): add row bit4 to the swizzle:
//     swz(row) = (row&7) ^ (((row>>4)&1)<<2)
//     so distance-16 lane pairs differ by bank-quad 4. Distance-32/48
//     pairs already differ via chunk bit0. Stage + read use the same
//     involution. 16x16 kernels (rt1/t2_splitk) keep the R5 swizzle.
// ---------------------------------------------------------------------------

// ---------------------------------------------------------------------------
// fc1: 128x128 tiled MFMA GEMM, 32x32x16 fragments.
// C = relu([A0|A1] @ [B0;B1]^T + bias), bf16 out. Block=256 (4 waves, 2x2,
// each wave 64x64 = 2x2 fragments of 32x32).
// C/D: col=lane&31, row=(reg&3)+8*(reg>>2)+4*(lane>>5)  [m74/m101 verified].
// ---------------------------------------------------------------------------
__global__ __launch_bounds__(256)
void gemm_bt(const bf16* __restrict__ A0, int lda0, int K0,
             const bf16* __restrict__ A1, int lda1, int K1,
             const bf16* __restrict__ B0, int ldb0,
             const bf16* __restrict__ B1, int ldb1,
             const float* __restrict__ bias,
             int relu,
             bf16* __restrict__ C, int ldc)
{
    __shared__ bf16 sA[128 * BK];
    __shared__ bf16 sB[128 * BK];

    const int t = threadIdx.x;
    const int w = t >> 6;
    const int l = t & 63;
    const int wm = w >> 1;
    const int wn = w & 1;
    const int r32 = l & 31;        // row within 32x32 fragment
    const int h   = l >> 5;        // k-half selector
    const int rowA0 = blockIdx.x * 128;
    const int rowB0 = blockIdx.y * 128;

    f32x16 acc[2][2];
#pragma unroll
    for (int i = 0; i < 2; ++i)
#pragma unroll
        for (int j = 0; j < 2; ++j)
#pragma unroll
            for (int e = 0; e < 16; ++e)
                acc[i][j][e] = 0.f;

    const int nK = (K0 + K1) >> 6;
    for (int kt = 0; kt < nK; ++kt) {
        const int k0 = kt << 6;
        const bf16 *Ap, *Bp;
        int la, lb, ks;
        if (k0 < K0) { Ap = A0; la = lda0; Bp = B0; lb = ldb0; ks = k0; }
        else         { Ap = A1; la = lda1; Bp = B1; lb = ldb1; ks = k0 - K0; }

        __syncthreads();
#pragma unroll
        for (int it = 0; it < 4; ++it) {
            const int L   = it * 256 + t;
            const int row = L >> 3;
            const int cb  = (L & 7) ^ (row & 7) ^ (((row >> 4) & 1) << 2);
            stage16(Ap + (size_t)(rowA0 + row) * la + ks + cb * 8,
                    sA + (size_t)(it * 256 + (w << 6)) * 8);
            stage16(Bp + (size_t)(rowB0 + row) * lb + ks + cb * 8,
                    sB + (size_t)(it * 256 + (w << 6)) * 8);
        }
        __syncthreads();

#pragma unroll
        for (int s = 0; s < 4; ++s) {              // 4 x K=16 sub-steps
            bf16x8 aF[2], bF[2];
#pragma unroll
            for (int i = 0; i < 2; ++i) {
                const int row = wm * 64 + i * 32 + r32;
                const int c   = (s * 2 + h) ^ (row & 7) ^ (((row >> 4) & 1) << 2);
                aF[i] = *(const bf16x8*)&sA[row * BK + c * 8];
            }
#pragma unroll
            for (int j = 0; j < 2; ++j) {
                const int row = wn * 64 + j * 32 + r32;
                const int c   = (s * 2 + h) ^ (row & 7) ^ (((row >> 4) & 1) << 2);
                bF[j] = *(const bf16x8*)&sB[row * BK + c * 8];
            }
#pragma unroll
            for (int i = 0; i < 2; ++i)
#pragma unroll
                for (int j = 0; j < 2; ++j)
                    acc[i][j] = __builtin_amdgcn_mfma_f32_32x32x16_bf16(
                        aF[i], bF[j], acc[i][j], 0, 0, 0);
        }
    }

    // C/D layout: col = lane&31, row = (reg&3) + 8*(reg>>2) + 4*h
#pragma unroll
    for (int i = 0; i < 2; ++i)
#pragma unroll
        for (int j = 0; j < 2; ++j) {
            const int col = rowB0 + wn * 64 + j * 32 + r32;
            const float bc = bias ? bias[col] : 0.f;
#pragma unroll
            for (int reg = 0; reg < 16; ++reg) {
                const int row = rowA0 + wm * 64 + i * 32 +
                                (reg & 3) + 8 * (reg >> 2) + 4 * h;
                float v = acc[i][j][reg] + bc;
                if (relu) v = v > 0.f ? v : 0.f;
                C[(size_t)row * ldc + col] = __float2bfloat16(v);
            }
        }
}

// ---------------------------------------------------------------------------
// fc2: 64x128 tile, fp32 out, 32x32x16 fragments. 768 balanced blocks.
// 4 waves 1x4; each wave 64x32 = 2x1 fragments of 32x32.
// ---------------------------------------------------------------------------
__global__ __launch_bounds__(256)
void gemm_bt64(const bf16* __restrict__ A0, int lda0, int K0,
               const bf16* __restrict__ A1, int lda1, int K1,
               const bf16* __restrict__ B0, int ldb0,
               const bf16* __restrict__ B1, int ldb1,
               const float* __restrict__ bias,
               float* __restrict__ Cf, int ldc)
{
    __shared__ bf16 sA[64 * BK];
    __shared__ bf16 sB[128 * BK];

    const int t = threadIdx.x;
    const int w = t >> 6;
    const int l = t & 63;
    const int wn = w;
    const int r32 = l & 31;
    const int h   = l >> 5;
    const int rowA0 = blockIdx.x * 64;
    const int rowB0 = blockIdx.y * 128;

    f32x16 acc[2];
#pragma unroll
    for (int i = 0; i < 2; ++i)
#pragma unroll
        for (int e = 0; e < 16; ++e)
            acc[i][e] = 0.f;

    const int nK = (K0 + K1) >> 6;
    for (int kt = 0; kt < nK; ++kt) {
        const int k0 = kt << 6;
        const bf16 *Ap, *Bp;
        int la, lb, ks;
        if (k0 < K0) { Ap = A0; la = lda0; Bp = B0; lb = ldb0; ks = k0; }
        else         { Ap = A1; la = lda1; Bp = B1; lb = ldb1; ks = k0 - K0; }

        __syncthreads();
#pragma unroll
        for (int it = 0; it < 2; ++it) {
            const int L   = it * 256 + t;
            const int row = L >> 3;
            const int cb  = (L & 7) ^ (row & 7) ^ (((row >> 4) & 1) << 2);
            stage16(Ap + (size_t)(rowA0 + row) * la + ks + cb * 8,
                    sA + (size_t)(it * 256 + (w << 6)) * 8);
        }
#pragma unroll
        for (int it = 0; it < 4; ++it) {
            const int L   = it * 256 + t;
            const int row = L >> 3;
            const int cb  = (L & 7) ^ (row & 7) ^ (((row >> 4) & 1) << 2);
            stage16(Bp + (size_t)(rowB0 + row) * lb + ks + cb * 8,
                    sB + (size_t)(it * 256 + (w << 6)) * 8);
        }
        __syncthreads();

#pragma unroll
        for (int s = 0; s < 4; ++s) {
            bf16x8 aF[2], bF;
#pragma unroll
            for (int i = 0; i < 2; ++i) {
                const int row = i * 32 + r32;
                const int c   = (s * 2 + h) ^ (row & 7) ^ (((row >> 4) & 1) << 2);
                aF[i] = *(const bf16x8*)&sA[row * BK + c * 8];
            }
            {
                const int row = wn * 32 + r32;
                const int c   = (s * 2 + h) ^ (row & 7) ^ (((row >> 4) & 1) << 2);
                bF = *(const bf16x8*)&sB[row * BK + c * 8];
            }
#pragma unroll
            for (int i = 0; i < 2; ++i)
                acc[i] = __builtin_amdgcn_mfma_f32_32x32x16_bf16(
                    aF[i], bF, acc[i], 0, 0, 0);
        }
    }

#pragma unroll
    for (int i = 0; i < 2; ++i) {
        const int col = rowB0 + wn * 32 + r32;
        const float bc = bias[col];
#pragma unroll
        for (int reg = 0; reg < 16; ++reg) {
            const int row = rowA0 + i * 32 + (reg & 3) + 8 * (reg >> 2) + 4 * h;
            Cf[(size_t)row * ldc + col] = acc[i][reg] + bc;
        }
    }
}

// ---------------------------------------------------------------------------
// Fused router + t1 GEMM, 64-row tiles (384 blocks for TLP).
// B = [gate_w1 ; SVH1] contiguous [384,768]. Grid (128, 3), K=768 full.
//   y=0,1 (router): bias+relu+64-row sum -> atomicAdd gsum[16,256].
//   y=2   (t1):     raw fp32 x@SVH1^T -> t1acc (non-atomic).
// Keeps 16x16 MFMA + R5 swizzle (measured conflict-free).
// ---------------------------------------------------------------------------
__global__ __launch_bounds__(256)
void rt1_kernel(const bf16* __restrict__ A, int lda,
                const bf16* __restrict__ B, int ldb,
                const float* __restrict__ gate_b1,
                float* __restrict__ gsum, float* __restrict__ t1acc)
{
    __shared__ bf16 sA[64 * BK];
    __shared__ bf16 sB[128 * BK];

    const int t = threadIdx.x;
    const int w = t >> 6;
    const int l = t & 63;
    const int wn = w;
    const int r = l & 15;
    const int q = l >> 4;
    const int sw = r & 7;
    const int rowA0 = blockIdx.x * 64;
    const int rowB0 = blockIdx.y * 128;
    const int b = rowA0 >> 9;

    f32x4 acc[4][2];
#pragma unroll
    for (int i = 0; i < 4; ++i)
#pragma unroll
        for (int j = 0; j < 2; ++j)
            acc[i][j] = (f32x4){0.f, 0.f, 0.f, 0.f};

    for (int kt = 0; kt < 12; ++kt) {      // K = 768
        const int ks = kt << 6;

        __syncthreads();
#pragma unroll
        for (int it = 0; it < 2; ++it) {
            const int L   = it * 256 + t;
            const int row = L >> 3;
            const int cb  = (L & 7) ^ (row & 7);
            stage16(A + (size_t)(rowA0 + row) * lda + ks + cb * 8,
                    sA + (size_t)(it * 256 + (w << 6)) * 8);
        }
#pragma unroll
        for (int it = 0; it < 4; ++it) {
            const int L   = it * 256 + t;
            const int row = L >> 3;
            const int cb  = (L & 7) ^ (row & 7);
            stage16(B + (size_t)(rowB0 + row) * ldb + ks + cb * 8,
                    sB + (size_t)(it * 256 + (w << 6)) * 8);
        }
        __syncthreads();

#pragma unroll
        for (int kk = 0; kk < 2; ++kk) {
            const int ch = ((kk * 4 + q) ^ sw) * 8;
            bf16x8 aF[4], bF[2];
#pragma unroll
            for (int i = 0; i < 4; ++i)
                aF[i] = *(const bf16x8*)&sA[(i * 16 + r) * BK + ch];
#pragma unroll
            for (int j = 0; j < 2; ++j)
                bF[j] = *(const bf16x8*)&sB[(wn * 32 + j * 16 + r) * BK + ch];
#pragma unroll
            for (int i = 0; i < 4; ++i)
#pragma unroll
                for (int j = 0; j < 2; ++j)
                    acc[i][j] = __builtin_amdgcn_mfma_f32_16x16x32_bf16(
                        aF[i], bF[j], acc[i][j], 0, 0, 0);
        }
    }

    if (rowB0 < 256) {
#pragma unroll
        for (int j = 0; j < 2; ++j) {
            const int col = rowB0 + wn * 32 + j * 16 + r;
            const float bc = gate_b1[col];
            float s = 0.f;
#pragma unroll
            for (int i = 0; i < 4; ++i)
#pragma unroll
                for (int rr = 0; rr < 4; ++rr) {
                    const float v = acc[i][j][rr] + bc;
                    s += v > 0.f ? v : 0.f;
                }
            s += __shfl_xor(s, 16, 64);
            s += __shfl_xor(s, 32, 64);
            if (q == 0) atomicAdd(&gsum[b * 256 + col], s);
        }
    } else {
#pragma unroll
        for (int i = 0; i < 4; ++i)
#pragma unroll
            for (int j = 0; j < 2; ++j)
#pragma unroll
                for (int rr = 0; rr < 4; ++rr) {
                    const int row = rowA0 + i * 16 + q * 4 + rr;
                    const int col = wn * 32 + j * 16 + r;
                    t1acc[(size_t)row * 128 + col] = acc[i][j][rr];
                }
    }
}

// ---------------------------------------------------------------------------
// t2 split-K: grid (128, 1, 8), 64x128 tiles, 6 K-tiles per z, atomicAdd
// into pre-zeroed t2acc fp32. 1024 blocks = 4/CU for latency hiding.
// Keeps 16x16 MFMA + R5 swizzle (measured conflict-free).
// ---------------------------------------------------------------------------
__global__ __launch_bounds__(256)
void t2_splitk(const bf16* __restrict__ A, int lda,
               const bf16* __restrict__ B, int ldb,
               float* __restrict__ Cacc)
{
    __shared__ bf16 sA[64 * BK];
    __shared__ bf16 sB[128 * BK];

    const int t = threadIdx.x;
    const int w = t >> 6;
    const int l = t & 63;
    const int wn = w;
    const int r = l & 15;
    const int q = l >> 4;
    const int sw = r & 7;
    const int rowA0 = blockIdx.x * 64;
    const int ksbase = blockIdx.z * 6 * BK;

    f32x4 acc[4][2];
#pragma unroll
    for (int i = 0; i < 4; ++i)
#pragma unroll
        for (int j = 0; j < 2; ++j)
            acc[i][j] = (f32x4){0.f, 0.f, 0.f, 0.f};

    for (int kt = 0; kt < 6; ++kt) {
        const int ks = ksbase + kt * BK;

        __syncthreads();
#pragma unroll
        for (int it = 0; it < 2; ++it) {
            const int L   = it * 256 + t;
            const int row = L >> 3;
            const int cb  = (L & 7) ^ (row & 7);
            stage16(A + (size_t)(rowA0 + row) * lda + ks + cb * 8,
                    sA + (size_t)(it * 256 + (w << 6)) * 8);
        }
#pragma unroll
        for (int it = 0; it < 4; ++it) {
            const int L   = it * 256 + t;
            const int row = L >> 3;
            const int cb  = (L & 7) ^ (row & 7);
            stage16(B + (size_t)row * ldb + ks + cb * 8,
                    sB + (size_t)(it * 256 + (w << 6)) * 8);
        }
        __syncthreads();

#pragma unroll
        for (int kk = 0; kk < 2; ++kk) {
            const int ch = ((kk * 4 + q) ^ sw) * 8;
            bf16x8 aF[4], bF[2];
#pragma unroll
            for (int i = 0; i < 4; ++i)
                aF[i] = *(const bf16x8*)&sA[(i * 16 + r) * BK + ch];
#pragma unroll
            for (int j = 0; j < 2; ++j)
                bF[j] = *(const bf16x8*)&sB[(wn * 32 + j * 16 + r) * BK + ch];
#pragma unroll
            for (int i = 0; i < 4; ++i)
#pragma unroll
                for (int j = 0; j < 2; ++j)
                    acc[i][j] = __builtin_amdgcn_mfma_f32_16x16x32_bf16(
                        aF[i], bF[j], acc[i][j], 0, 0, 0);
        }
    }

#pragma unroll
    for (int i = 0; i < 4; ++i)
#pragma unroll
        for (int j = 0; j < 2; ++j)
#pragma unroll
            for (int rr = 0; rr < 4; ++rr) {
                const int row = rowA0 + i * 16 + q * 4 + rr;
                const int col = wn * 32 + j * 16 + r;
                atomicAdd(&Cacc[(size_t)row * 128 + col], acc[i][j][rr]);
            }
}

// t[i] = bf16(acc[i] * gw[batch(row)][col])   (M x 128)
__global__ void scale_cvt_kernel(const float* __restrict__ acc,
                                 const float* __restrict__ gw,
                                 bf16* __restrict__ outb)
{
    const int i = blockIdx.x * 256 + threadIdx.x;
    const int col = i & 127;
    const int row = i >> 7;
    outb[i] = __float2bfloat16(acc[i] * gw[(row >> 9) * 128 + col]);
}

// ---------------------------------------------------------------------------
// Fused prep: fp32->bf16 casts + coalesced LDS-tile U transposes + merged
// biases + zeroing of gsum and t2acc. One launch.
// ---------------------------------------------------------------------------
__device__ __forceinline__ void cvt_range(const float* src, bf16* dst, int base, int t)
{
    const int i = base * 256 + t;
    const float4 v = ((const float4*)src)[i];
    ((bf16x4*)dst)[i] = (bf16x4){(__bf16)v.x, (__bf16)v.y, (__bf16)v.z, (__bf16)v.w};
}

__device__ __forceinline__ void transpose_tile(const float* U, bf16* UT, int F,
                                               int bx, int by, int t,
                                               float (*sh)[65])
{
    const int f0 = bx * 64, ek0 = by * 64;
#pragma unroll
    for (int i = 0; i < 16; ++i) {
        const int row = i * 4 + (t >> 6);
        const int col = t & 63;
        sh[row][col] = U[(size_t)(ek0 + row) * F + f0 + col];
    }
    __syncthreads();
#pragma unroll
    for (int i = 0; i < 16; ++i) {
        const int row = i * 4 + (t >> 6);
        const int col = t & 63;
        UT[(size_t)(f0 + row) * 128 + ek0 + col] = __float2bfloat16(sh[col][row]);
    }
}

__global__ void prep_all(const float* __restrict__ x,    bf16* __restrict__ xb,
                         const float* __restrict__ W1,   bf16* __restrict__ W1b,
                         const float* __restrict__ W2,   bf16* __restrict__ W2b,
                         const float* __restrict__ gw1,  bf16* __restrict__ gw1b,
                         const float* __restrict__ gw2,  bf16* __restrict__ gw2b,
                         const float* __restrict__ SVH1, bf16* __restrict__ svh1b,
                         const float* __restrict__ SVH2, bf16* __restrict__ svh2b,
                         const float* __restrict__ U1,   bf16* __restrict__ U1T,
                         const float* __restrict__ U2,   bf16* __restrict__ U2T,
                         const float* __restrict__ b1,   const float* __restrict__ TB1,
                         const float* __restrict__ b2,   const float* __restrict__ TB2,
                         float* __restrict__ b1m, float* __restrict__ b2m,
                         float* __restrict__ gsum, float* __restrict__ t2acc)
{
    __shared__ float sh[64][65];
    const int b = blockIdx.x;
    const int t = threadIdx.x;
    if      (b < 6144)  cvt_range(x,   xb,   b,         t);
    else if (b < 8448)  cvt_range(W1,  W1b,  b - 6144,  t);
    else if (b < 10752) cvt_range(W2,  W2b,  b - 8448,  t);
    else if (b < 10944) cvt_range(gw1, gw1b, b - 10752, t);
    else if (b < 10976) cvt_range(gw2, gw2b, b - 10944, t);
    else if (b < 11072) cvt_range(SVH1, svh1b, b - 10976, t);
    else if (b < 11456) cvt_range(SVH2, svh2b, b - 11072, t);
    else if (b < 11552) {          // U1 [128,3072] -> U1T: 48 x 2 tiles
        const int b2 = b - 11456;
        transpose_tile(U1, U1T, 3072, b2 >> 1, b2 & 1, t, sh);
    } else if (b < 11576) {        // U2 [128,768] -> U2T: 12 x 2 tiles
        const int b2 = b - 11552;
        transpose_tile(U2, U2T, 768, b2 >> 1, b2 & 1, t, sh);
    } else if (b < 11591) {        // merged biases
        const int i = (b - 11576) * 256 + t;
        if (i < 3072) {
            float s = 0.f;
            for (int e = 0; e < 8; ++e) s += TB1[e * 3072 + i];
            b1m[i] = b1[i] + 0.2f * s;
        } else if (i < 3840) {
            const int j = i - 3072;
            float s = 0.f;
            for (int e = 0; e < 8; ++e) s += TB2[e * 768 + j];
            b2m[j] = b2[j] + 0.2f * s;
        }
    } else if (b < 11607) {        // zero gsum[4096]
        const int i = (b - 11591) * 256 + t;
        gsum[i] = 0.f;
    } else {                       // zero t2acc: 1M floats as float4
        const int i = (b - 11607) * 256 + t;
        ((float4*)t2acc)[i] = (float4){0.f, 0.f, 0.f, 0.f};
    }
}

// gw[b,c] = gate_b2[c] + (1/512) * sum_j gsum[b,j] * gate_w2[c,j]
__global__ void gw_kernel(const float* __restrict__ gsum, const bf16* __restrict__ gw2b,
                          const float* __restrict__ gate_b2, float* __restrict__ gw)
{
    const int b = blockIdx.x;
    const int c = threadIdx.x;
    float s = 0.f;
    for (int j = 0; j < 256; ++j)
        s += gsum[b * 256 + j] * __bfloat162float(gw2b[c * 256 + j]);
    gw[b * 128 + c] = gate_b2[c] + s * (1.0f / 512.0f);
}

// ---------------------------------------------------------------------------
extern "C" void kernel_launch(void* const* d_in, const int* in_sizes, int n_in,
                              void* d_out, int out_size, void* d_ws, size_t ws_size,
                              hipStream_t stream)
{
    const float* x       = (const float*)d_in[0];
    const float* gate_w1 = (const float*)d_in[1];
    const float* gate_b1 = (const float*)d_in[2];
    const float* gate_w2 = (const float*)d_in[3];
    const float* gate_b2 = (const float*)d_in[4];
    const float* W1      = (const float*)d_in[5];
    const float* b1      = (const float*)d_in[6];
    const float* W2      = (const float*)d_in[7];
    const float* b2      = (const float*)d_in[8];
    const float* U1      = (const float*)d_in[9];
    const float* SVH1    = (const float*)d_in[10];
    const float* U2      = (const float*)d_in[11];
    const float* SVH2    = (const float*)d_in[12];
    const float* TB1     = (const float*)d_in[13];
    const float* TB2     = (const float*)d_in[14];
    float* out = (float*)d_out;                     // [8192, 768] fp32

    char* p = (char*)d_ws;
    auto alloc = [&](size_t bytes) {
        char* q = p;
        p += (bytes + 255) & ~(size_t)255;
        return q;
    };
    bf16* hbuf  = (bf16*)alloc((size_t)8192 * 3072 * 2);
    bf16* xb    = (bf16*)alloc((size_t)8192 * 768 * 2);
    bf16* t1buf = (bf16*)alloc((size_t)8192 * 128 * 2);
    bf16* t2buf = (bf16*)alloc((size_t)8192 * 128 * 2);
    bf16* W1b   = (bf16*)alloc((size_t)3072 * 768 * 2);
    bf16* W2b   = (bf16*)alloc((size_t)768 * 3072 * 2);
    // gw1b and svh1b MUST be contiguous: rt1_kernel treats them as one
    // [384, 768] B matrix. 256*768*2 = 393216 B (multiple of 256 -> no pad).
    bf16* gw1b  = (bf16*)alloc((size_t)256 * 768 * 2);
    bf16* svh1b = (bf16*)alloc((size_t)128 * 768 * 2);
    bf16* gw2b  = (bf16*)alloc((size_t)128 * 256 * 2);
    bf16* svh2b = (bf16*)alloc((size_t)128 * 3072 * 2);
    bf16* U1T   = (bf16*)alloc((size_t)3072 * 128 * 2);
    bf16* U2T   = (bf16*)alloc((size_t)768 * 128 * 2);
    float* gsum = (float*)alloc(16 * 256 * 4);
    float* gw   = (float*)alloc(2048 * 4);
    float* b1m  = (float*)alloc(3072 * 4);
    float* b2m  = (float*)alloc(768 * 4);
    float* t1acc = (float*)alloc((size_t)8192 * 128 * 4);
    float* t2acc = (float*)alloc((size_t)8192 * 128 * 4);

    const dim3 blk(256);

    prep_all<<<12631, blk, 0, stream>>>(x, xb, W1, W1b, W2, W2b,
                                        gate_w1, gw1b, gate_w2, gw2b,
                                        SVH1, svh1b, SVH2, svh2b,
                                        U1, U1T, U2, U2T,
                                        b1, TB1, b2, TB2, b1m, b2m,
                                        gsum, t2acc);

    // fused router + t1raw (64-row tiles, 384 blocks)
    rt1_kernel<<<dim3(128, 3), blk, 0, stream>>>(xb, 768, gw1b, 768,
                                                 gate_b1, gsum, t1acc);
    // gw = gsum/512 @ gate_w2^T + gate_b2              [16, 128]
    gw_kernel<<<16, 128, 0, stream>>>(gsum, gw2b, gate_b2, gw);
    // t1 = t1acc * gw -> bf16
    scale_cvt_kernel<<<4096, blk, 0, stream>>>(t1acc, gw, t1buf);

    // h = relu([x|t1] @ [W1|U1T]^T + b1m)              [8192, 3072]
    gemm_bt<<<dim3(64, 24), blk, 0, stream>>>(xb, 768, 768, t1buf, 128, 128,
                                              W1b, 768, U1T, 128,
                                              b1m, 1, hbuf, 3072);

    // t2acc += h @ SVH2^T  (split-K z=8, 1024 blocks)  [8192, 128]
    t2_splitk<<<dim3(128, 1, 8), blk, 0, stream>>>(hbuf, 3072, svh2b, 3072, t2acc);
    // t2 = t2acc * gw -> bf16
    scale_cvt_kernel<<<4096, blk, 0, stream>>>(t2acc, gw, t2buf);

    // out = [h|t2] @ [W2|U2T]^T + b2m  (fp32 out)      [8192, 768]
    gemm_bt64<<<dim3(128, 6), blk, 0, stream>>>(hbuf, 3072, 3072, t2buf, 128, 128,
                                                W2b, 3072, U2T, 128,
                                                b2m, out, 768);
}

// Round 4
// 261.326 us; speedup vs baseline: 1.1771x; 1.0776x over previous
//
#include <hip/hip_runtime.h>
#include <hip/hip_bf16.h>

using bf16 = __hip_bfloat16;
typedef __bf16 bf16x8 __attribute__((ext_vector_type(8)));
typedef __bf16 bf16x4 __attribute__((ext_vector_type(4)));
typedef float f32x4 __attribute__((ext_vector_type(4)));
typedef float f32x16 __attribute__((ext_vector_type(16)));

#define BK 64

// ---------------------------------------------------------------------------
// Staging helper: 16B per lane via global_load_lds, wave-uniform LDS base.
// ---------------------------------------------------------------------------
__device__ __forceinline__ void stage16(const bf16* gsrc, bf16* lds_base)
{
    __builtin_amdgcn_global_load_lds(
        (__attribute__((address_space(1))) void*)(void*)gsrc,
        (__attribute__((address_space(3))) void*)(void*)lds_base,
        16, 0, 0);
}

// LDS chunk swizzle history:
// R5: slot (row,c) holds chunk c^(row&7) — killed 16-way conflict for the
//     16x16 read pattern (1.65e7 -> 0).
// R11: 256^2 8-phase schedule regressed (grid quantization + short K).
// R12: 32x32x16 MFMA halved instruction count (fc1 67->62.6us) but added
//     5.5e6 conflict-cycles (4 cyc/ds_read_b128).
// R13: row-bit4 XOR left the count BIT-IDENTICAL -> conflict group is the
//     32-lane half-wave: a 32x32 fragment read has all 32 lanes on one
//     k-chunk; any 3-bit row-XOR gives 4 lanes/bank-quad. This is a floor
//     for b128 reads of 32x32 frags (~2-5us, partly hidden). ACCEPTED.
// R14 (this round): de-atomicize t2 split-K (partials + fused reduce),
//     rebalance rt1 to 768 blocks (3.0 rounds), drop t2acc zeroing.
// ---------------------------------------------------------------------------

// ---------------------------------------------------------------------------
// fc1: 128x128 tiled MFMA GEMM, 32x32x16 fragments.
// C = relu([A0|A1] @ [B0;B1]^T + bias), bf16 out. Block=256 (4 waves, 2x2,
// each wave 64x64 = 2x2 fragments of 32x32).
// C/D: col=lane&31, row=(reg&3)+8*(reg>>2)+4*(lane>>5)  [m74/m101 verified].
// ---------------------------------------------------------------------------
__global__ __launch_bounds__(256)
void gemm_bt(const bf16* __restrict__ A0, int lda0, int K0,
             const bf16* __restrict__ A1, int lda1, int K1,
             const bf16* __restrict__ B0, int ldb0,
             const bf16* __restrict__ B1, int ldb1,
             const float* __restrict__ bias,
             int relu,
             bf16* __restrict__ C, int ldc)
{
    __shared__ bf16 sA[128 * BK];
    __shared__ bf16 sB[128 * BK];

    const int t = threadIdx.x;
    const int w = t >> 6;
    const int l = t & 63;
    const int wm = w >> 1;
    const int wn = w & 1;
    const int r32 = l & 31;        // row within 32x32 fragment
    const int h   = l >> 5;        // k-half selector
    const int rowA0 = blockIdx.x * 128;
    const int rowB0 = blockIdx.y * 128;

    f32x16 acc[2][2];
#pragma unroll
    for (int i = 0; i < 2; ++i)
#pragma unroll
        for (int j = 0; j < 2; ++j)
#pragma unroll
            for (int e = 0; e < 16; ++e)
                acc[i][j][e] = 0.f;

    const int nK = (K0 + K1) >> 6;
    for (int kt = 0; kt < nK; ++kt) {
        const int k0 = kt << 6;
        const bf16 *Ap, *Bp;
        int la, lb, ks;
        if (k0 < K0) { Ap = A0; la = lda0; Bp = B0; lb = ldb0; ks = k0; }
        else         { Ap = A1; la = lda1; Bp = B1; lb = ldb1; ks = k0 - K0; }

        __syncthreads();
#pragma unroll
        for (int it = 0; it < 4; ++it) {
            const int L   = it * 256 + t;
            const int row = L >> 3;
            const int cb  = (L & 7) ^ (row & 7);   // swizzled source chunk
            stage16(Ap + (size_t)(rowA0 + row) * la + ks + cb * 8,
                    sA + (size_t)(it * 256 + (w << 6)) * 8);
            stage16(Bp + (size_t)(rowB0 + row) * lb + ks + cb * 8,
                    sB + (size_t)(it * 256 + (w << 6)) * 8);
        }
        __syncthreads();

#pragma unroll
        for (int s = 0; s < 4; ++s) {              // 4 x K=16 sub-steps
            bf16x8 aF[2], bF[2];
#pragma unroll
            for (int i = 0; i < 2; ++i) {
                const int row = wm * 64 + i * 32 + r32;
                const int c   = (s * 2 + h) ^ (row & 7);
                aF[i] = *(const bf16x8*)&sA[row * BK + c * 8];
            }
#pragma unroll
            for (int j = 0; j < 2; ++j) {
                const int row = wn * 64 + j * 32 + r32;
                const int c   = (s * 2 + h) ^ (row & 7);
                bF[j] = *(const bf16x8*)&sB[row * BK + c * 8];
            }
#pragma unroll
            for (int i = 0; i < 2; ++i)
#pragma unroll
                for (int j = 0; j < 2; ++j)
                    acc[i][j] = __builtin_amdgcn_mfma_f32_32x32x16_bf16(
                        aF[i], bF[j], acc[i][j], 0, 0, 0);
        }
    }

    // C/D layout: col = lane&31, row = (reg&3) + 8*(reg>>2) + 4*h
#pragma unroll
    for (int i = 0; i < 2; ++i)
#pragma unroll
        for (int j = 0; j < 2; ++j) {
            const int col = rowB0 + wn * 64 + j * 32 + r32;
            const float bc = bias ? bias[col] : 0.f;
#pragma unroll
            for (int reg = 0; reg < 16; ++reg) {
                const int row = rowA0 + wm * 64 + i * 32 +
                                (reg & 3) + 8 * (reg >> 2) + 4 * h;
                float v = acc[i][j][reg] + bc;
                if (relu) v = v > 0.f ? v : 0.f;
                C[(size_t)row * ldc + col] = __float2bfloat16(v);
            }
        }
}

// ---------------------------------------------------------------------------
// fc2: 64x128 tile, fp32 out, 32x32x16 fragments. 768 balanced blocks.
// 4 waves 1x4; each wave 64x32 = 2x1 fragments of 32x32.
// ---------------------------------------------------------------------------
__global__ __launch_bounds__(256)
void gemm_bt64(const bf16* __restrict__ A0, int lda0, int K0,
               const bf16* __restrict__ A1, int lda1, int K1,
               const bf16* __restrict__ B0, int ldb0,
               const bf16* __restrict__ B1, int ldb1,
               const float* __restrict__ bias,
               float* __restrict__ Cf, int ldc)
{
    __shared__ bf16 sA[64 * BK];
    __shared__ bf16 sB[128 * BK];

    const int t = threadIdx.x;
    const int w = t >> 6;
    const int l = t & 63;
    const int wn = w;
    const int r32 = l & 31;
    const int h   = l >> 5;
    const int rowA0 = blockIdx.x * 64;
    const int rowB0 = blockIdx.y * 128;

    f32x16 acc[2];
#pragma unroll
    for (int i = 0; i < 2; ++i)
#pragma unroll
        for (int e = 0; e < 16; ++e)
            acc[i][e] = 0.f;

    const int nK = (K0 + K1) >> 6;
    for (int kt = 0; kt < nK; ++kt) {
        const int k0 = kt << 6;
        const bf16 *Ap, *Bp;
        int la, lb, ks;
        if (k0 < K0) { Ap = A0; la = lda0; Bp = B0; lb = ldb0; ks = k0; }
        else         { Ap = A1; la = lda1; Bp = B1; lb = ldb1; ks = k0 - K0; }

        __syncthreads();
#pragma unroll
        for (int it = 0; it < 2; ++it) {
            const int L   = it * 256 + t;
            const int row = L >> 3;
            const int cb  = (L & 7) ^ (row & 7);
            stage16(Ap + (size_t)(rowA0 + row) * la + ks + cb * 8,
                    sA + (size_t)(it * 256 + (w << 6)) * 8);
        }
#pragma unroll
        for (int it = 0; it < 4; ++it) {
            const int L   = it * 256 + t;
            const int row = L >> 3;
            const int cb  = (L & 7) ^ (row & 7);
            stage16(Bp + (size_t)(rowB0 + row) * lb + ks + cb * 8,
                    sB + (size_t)(it * 256 + (w << 6)) * 8);
        }
        __syncthreads();

#pragma unroll
        for (int s = 0; s < 4; ++s) {
            bf16x8 aF[2], bF;
#pragma unroll
            for (int i = 0; i < 2; ++i) {
                const int row = i * 32 + r32;
                const int c   = (s * 2 + h) ^ (row & 7);
                aF[i] = *(const bf16x8*)&sA[row * BK + c * 8];
            }
            {
                const int row = wn * 32 + r32;
                const int c   = (s * 2 + h) ^ (row & 7);
                bF = *(const bf16x8*)&sB[row * BK + c * 8];
            }
#pragma unroll
            for (int i = 0; i < 2; ++i)
                acc[i] = __builtin_amdgcn_mfma_f32_32x32x16_bf16(
                    aF[i], bF, acc[i], 0, 0, 0);
        }
    }

#pragma unroll
    for (int i = 0; i < 2; ++i) {
        const int col = rowB0 + wn * 32 + r32;
        const float bc = bias[col];
#pragma unroll
        for (int reg = 0; reg < 16; ++reg) {
            const int row = rowA0 + i * 32 + (reg & 3) + 8 * (reg >> 2) + 4 * h;
            Cf[(size_t)row * ldc + col] = acc[i][reg] + bc;
        }
    }
}

// ---------------------------------------------------------------------------
// Fused router + t1 GEMM, 64x64 tiles. B = [gate_w1 ; SVH1] contiguous
// [384,768]. Grid (128, 6) = 768 blocks = 3.0 even rounds/CU (R14: was
// (128,3)=384 = 1.5 rounds, half-idle second round).
//   y=0..3 (router): bias+relu+64-row sum -> atomicAdd gsum[16,256].
//   y=4,5  (t1):     raw fp32 x@SVH1^T -> t1acc (non-atomic).
// 4 waves 2x2; each wave 32x32 = 2x2 frags of 16x16 (R5 swizzle, clean).
// ---------------------------------------------------------------------------
__global__ __launch_bounds__(256)
void rt1_kernel(const bf16* __restrict__ A, int lda,
                const bf16* __restrict__ B, int ldb,
                const float* __restrict__ gate_b1,
                float* __restrict__ gsum, float* __restrict__ t1acc)
{
    __shared__ bf16 sA[64 * BK];
    __shared__ bf16 sB[64 * BK];

    const int t = threadIdx.x;
    const int w = t >> 6;
    const int l = t & 63;
    const int wm = w >> 1;
    const int wn = w & 1;
    const int r = l & 15;
    const int q = l >> 4;
    const int sw = r & 7;
    const int rowA0 = blockIdx.x * 64;
    const int rowB0 = blockIdx.y * 64;
    const int b = rowA0 >> 9;

    f32x4 acc[2][2];
#pragma unroll
    for (int i = 0; i < 2; ++i)
#pragma unroll
        for (int j = 0; j < 2; ++j)
            acc[i][j] = (f32x4){0.f, 0.f, 0.f, 0.f};

    for (int kt = 0; kt < 12; ++kt) {      // K = 768
        const int ks = kt << 6;

        __syncthreads();
#pragma unroll
        for (int it = 0; it < 2; ++it) {
            const int L   = it * 256 + t;
            const int row = L >> 3;
            const int cb  = (L & 7) ^ (row & 7);
            stage16(A + (size_t)(rowA0 + row) * lda + ks + cb * 8,
                    sA + (size_t)(it * 256 + (w << 6)) * 8);
            stage16(B + (size_t)(rowB0 + row) * ldb + ks + cb * 8,
                    sB + (size_t)(it * 256 + (w << 6)) * 8);
        }
        __syncthreads();

#pragma unroll
        for (int kk = 0; kk < 2; ++kk) {
            const int ch = ((kk * 4 + q) ^ sw) * 8;
            bf16x8 aF[2], bF[2];
#pragma unroll
            for (int i = 0; i < 2; ++i)
                aF[i] = *(const bf16x8*)&sA[(wm * 32 + i * 16 + r) * BK + ch];
#pragma unroll
            for (int j = 0; j < 2; ++j)
                bF[j] = *(const bf16x8*)&sB[(wn * 32 + j * 16 + r) * BK + ch];
#pragma unroll
            for (int i = 0; i < 2; ++i)
#pragma unroll
                for (int j = 0; j < 2; ++j)
                    acc[i][j] = __builtin_amdgcn_mfma_f32_16x16x32_bf16(
                        aF[i], bF[j], acc[i][j], 0, 0, 0);
        }
    }

    if (rowB0 < 256) {
        // router: relu + per-wave 32-row sum; two wm-waves atomically merge
#pragma unroll
        for (int j = 0; j < 2; ++j) {
            const int col = rowB0 + wn * 32 + j * 16 + r;
            const float bc = gate_b1[col];
            float s = 0.f;
#pragma unroll
            for (int i = 0; i < 2; ++i)
#pragma unroll
                for (int rr = 0; rr < 4; ++rr) {
                    const float v = acc[i][j][rr] + bc;
                    s += v > 0.f ? v : 0.f;
                }
            s += __shfl_xor(s, 16, 64);
            s += __shfl_xor(s, 32, 64);
            if (q == 0) atomicAdd(&gsum[b * 256 + col], s);
        }
    } else {
#pragma unroll
        for (int i = 0; i < 2; ++i)
#pragma unroll
            for (int j = 0; j < 2; ++j)
#pragma unroll
                for (int rr = 0; rr < 4; ++rr) {
                    const int row = rowA0 + wm * 32 + i * 16 + q * 4 + rr;
                    const int col = (rowB0 - 256) + wn * 32 + j * 16 + r;
                    t1acc[(size_t)row * 128 + col] = acc[i][j][rr];
                }
    }
}

// ---------------------------------------------------------------------------
// t2 split-K: grid (128, 1, 4), 64x128 tiles, 12 K-tiles per z, NON-ATOMIC
// per-z partial stores (R14: was z=8 with 8.4M global fp32 atomicAdds).
// Cpart layout [4][8192][128] fp32.
// ---------------------------------------------------------------------------
__global__ __launch_bounds__(256)
void t2_splitk(const bf16* __restrict__ A, int lda,
               const bf16* __restrict__ B, int ldb,
               float* __restrict__ Cpart)
{
    __shared__ bf16 sA[64 * BK];
    __shared__ bf16 sB[128 * BK];

    const int t = threadIdx.x;
    const int w = t >> 6;
    const int l = t & 63;
    const int wn = w;
    const int r = l & 15;
    const int q = l >> 4;
    const int sw = r & 7;
    const int rowA0 = blockIdx.x * 64;
    const int z = blockIdx.z;
    const int ksbase = z * 12 * BK;
    float* Cz = Cpart + (size_t)z * 8192 * 128;

    f32x4 acc[4][2];
#pragma unroll
    for (int i = 0; i < 4; ++i)
#pragma unroll
        for (int j = 0; j < 2; ++j)
            acc[i][j] = (f32x4){0.f, 0.f, 0.f, 0.f};

    for (int kt = 0; kt < 12; ++kt) {
        const int ks = ksbase + kt * BK;

        __syncthreads();
#pragma unroll
        for (int it = 0; it < 2; ++it) {
            const int L   = it * 256 + t;
            const int row = L >> 3;
            const int cb  = (L & 7) ^ (row & 7);
            stage16(A + (size_t)(rowA0 + row) * lda + ks + cb * 8,
                    sA + (size_t)(it * 256 + (w << 6)) * 8);
        }
#pragma unroll
        for (int it = 0; it < 4; ++it) {
            const int L   = it * 256 + t;
            const int row = L >> 3;
            const int cb  = (L & 7) ^ (row & 7);
            stage16(B + (size_t)row * ldb + ks + cb * 8,
                    sB + (size_t)(it * 256 + (w << 6)) * 8);
        }
        __syncthreads();

#pragma unroll
        for (int kk = 0; kk < 2; ++kk) {
            const int ch = ((kk * 4 + q) ^ sw) * 8;
            bf16x8 aF[4], bF[2];
#pragma unroll
            for (int i = 0; i < 4; ++i)
                aF[i] = *(const bf16x8*)&sA[(i * 16 + r) * BK + ch];
#pragma unroll
            for (int j = 0; j < 2; ++j)
                bF[j] = *(const bf16x8*)&sB[(wn * 32 + j * 16 + r) * BK + ch];
#pragma unroll
            for (int i = 0; i < 4; ++i)
#pragma unroll
                for (int j = 0; j < 2; ++j)
                    acc[i][j] = __builtin_amdgcn_mfma_f32_16x16x32_bf16(
                        aF[i], bF[j], acc[i][j], 0, 0, 0);
        }
    }

#pragma unroll
    for (int i = 0; i < 4; ++i)
#pragma unroll
        for (int j = 0; j < 2; ++j)
#pragma unroll
            for (int rr = 0; rr < 4; ++rr) {
                const int row = rowA0 + i * 16 + q * 4 + rr;
                const int col = wn * 32 + j * 16 + r;
                Cz[(size_t)row * 128 + col] = acc[i][j][rr];
            }
}

// t[i] = bf16(acc[i] * gw[batch(row)][col])   (M x 128)
__global__ void scale_cvt_kernel(const float* __restrict__ acc,
                                 const float* __restrict__ gw,
                                 bf16* __restrict__ outb)
{
    const int i = blockIdx.x * 256 + threadIdx.x;
    const int col = i & 127;
    const int row = i >> 7;
    outb[i] = __float2bfloat16(acc[i] * gw[(row >> 9) * 128 + col]);
}

// t[i] = bf16((sum_z part[z][i]) * gw[batch(row)][col])   (reduce z=4)
__global__ void scale_red4_cvt(const float* __restrict__ part,
                               const float* __restrict__ gw,
                               bf16* __restrict__ outb)
{
    const int i = blockIdx.x * 256 + threadIdx.x;
    const int col = i & 127;
    const int row = i >> 7;
    const float s = part[i] + part[1048576 + i] +
                    part[2097152 + i] + part[3145728 + i];
    outb[i] = __float2bfloat16(s * gw[(row >> 9) * 128 + col]);
}

// ---------------------------------------------------------------------------
// Fused prep: fp32->bf16 casts + coalesced LDS-tile U transposes + merged
// biases + zeroing of gsum. One launch. (R14: t2acc zeroing removed.)
// ---------------------------------------------------------------------------
__device__ __forceinline__ void cvt_range(const float* src, bf16* dst, int base, int t)
{
    const int i = base * 256 + t;
    const float4 v = ((const float4*)src)[i];
    ((bf16x4*)dst)[i] = (bf16x4){(__bf16)v.x, (__bf16)v.y, (__bf16)v.z, (__bf16)v.w};
}

__device__ __forceinline__ void transpose_tile(const float* U, bf16* UT, int F,
                                               int bx, int by, int t,
                                               float (*sh)[65])
{
    const int f0 = bx * 64, ek0 = by * 64;
#pragma unroll
    for (int i = 0; i < 16; ++i) {
        const int row = i * 4 + (t >> 6);
        const int col = t & 63;
        sh[row][col] = U[(size_t)(ek0 + row) * F + f0 + col];
    }
    __syncthreads();
#pragma unroll
    for (int i = 0; i < 16; ++i) {
        const int row = i * 4 + (t >> 6);
        const int col = t & 63;
        UT[(size_t)(f0 + row) * 128 + ek0 + col] = __float2bfloat16(sh[col][row]);
    }
}

__global__ void prep_all(const float* __restrict__ x,    bf16* __restrict__ xb,
                         const float* __restrict__ W1,   bf16* __restrict__ W1b,
                         const float* __restrict__ W2,   bf16* __restrict__ W2b,
                         const float* __restrict__ gw1,  bf16* __restrict__ gw1b,
                         const float* __restrict__ gw2,  bf16* __restrict__ gw2b,
                         const float* __restrict__ SVH1, bf16* __restrict__ svh1b,
                         const float* __restrict__ SVH2, bf16* __restrict__ svh2b,
                         const float* __restrict__ U1,   bf16* __restrict__ U1T,
                         const float* __restrict__ U2,   bf16* __restrict__ U2T,
                         const float* __restrict__ b1,   const float* __restrict__ TB1,
                         const float* __restrict__ b2,   const float* __restrict__ TB2,
                         float* __restrict__ b1m, float* __restrict__ b2m,
                         float* __restrict__ gsum)
{
    __shared__ float sh[64][65];
    const int b = blockIdx.x;
    const int t = threadIdx.x;
    if      (b < 6144)  cvt_range(x,   xb,   b,         t);
    else if (b < 8448)  cvt_range(W1,  W1b,  b - 6144,  t);
    else if (b < 10752) cvt_range(W2,  W2b,  b - 8448,  t);
    else if (b < 10944) cvt_range(gw1, gw1b, b - 10752, t);
    else if (b < 10976) cvt_range(gw2, gw2b, b - 10944, t);
    else if (b < 11072) cvt_range(SVH1, svh1b, b - 10976, t);
    else if (b < 11456) cvt_range(SVH2, svh2b, b - 11072, t);
    else if (b < 11552) {          // U1 [128,3072] -> U1T: 48 x 2 tiles
        const int b2 = b - 11456;
        transpose_tile(U1, U1T, 3072, b2 >> 1, b2 & 1, t, sh);
    } else if (b < 11576) {        // U2 [128,768] -> U2T: 12 x 2 tiles
        const int b2 = b - 11552;
        transpose_tile(U2, U2T, 768, b2 >> 1, b2 & 1, t, sh);
    } else if (b < 11591) {        // merged biases
        const int i = (b - 11576) * 256 + t;
        if (i < 3072) {
            float s = 0.f;
            for (int e = 0; e < 8; ++e) s += TB1[e * 3072 + i];
            b1m[i] = b1[i] + 0.2f * s;
        } else if (i < 3840) {
            const int j = i - 3072;
            float s = 0.f;
            for (int e = 0; e < 8; ++e) s += TB2[e * 768 + j];
            b2m[j] = b2[j] + 0.2f * s;
        }
    } else {                       // zero gsum[4096]
        const int i = (b - 11591) * 256 + t;
        gsum[i] = 0.f;
    }
}

// gw[b,c] = gate_b2[c] + (1/512) * sum_j gsum[b,j] * gate_w2[c,j]
__global__ void gw_kernel(const float* __restrict__ gsum, const bf16* __restrict__ gw2b,
                          const float* __restrict__ gate_b2, float* __restrict__ gw)
{
    const int b = blockIdx.x;
    const int c = threadIdx.x;
    const bf16x8* wrow = (const bf16x8*)&gw2b[c * 256];
    const float* gs = &gsum[b * 256];
    float s = 0.f;
    for (int j8 = 0; j8 < 32; ++j8) {
        const bf16x8 v = wrow[j8];
#pragma unroll
        for (int e = 0; e < 8; ++e)
            s += gs[j8 * 8 + e] * (float)v[e];
    }
    gw[b * 128 + c] = gate_b2[c] + s * (1.0f / 512.0f);
}

// ---------------------------------------------------------------------------
extern "C" void kernel_launch(void* const* d_in, const int* in_sizes, int n_in,
                              void* d_out, int out_size, void* d_ws, size_t ws_size,
                              hipStream_t stream)
{
    const float* x       = (const float*)d_in[0];
    const float* gate_w1 = (const float*)d_in[1];
    const float* gate_b1 = (const float*)d_in[2];
    const float* gate_w2 = (const float*)d_in[3];
    const float* gate_b2 = (const float*)d_in[4];
    const float* W1      = (const float*)d_in[5];
    const float* b1      = (const float*)d_in[6];
    const float* W2      = (const float*)d_in[7];
    const float* b2      = (const float*)d_in[8];
    const float* U1      = (const float*)d_in[9];
    const float* SVH1    = (const float*)d_in[10];
    const float* U2      = (const float*)d_in[11];
    const float* SVH2    = (const float*)d_in[12];
    const float* TB1     = (const float*)d_in[13];
    const float* TB2     = (const float*)d_in[14];
    float* out = (float*)d_out;                     // [8192, 768] fp32

    char* p = (char*)d_ws;
    auto alloc = [&](size_t bytes) {
        char* q = p;
        p += (bytes + 255) & ~(size_t)255;
        return q;
    };
    bf16* hbuf  = (bf16*)alloc((size_t)8192 * 3072 * 2);
    bf16* xb    = (bf16*)alloc((size_t)8192 * 768 * 2);
    bf16* t1buf = (bf16*)alloc((size_t)8192 * 128 * 2);
    bf16* t2buf = (bf16*)alloc((size_t)8192 * 128 * 2);
    bf16* W1b   = (bf16*)alloc((size_t)3072 * 768 * 2);
    bf16* W2b   = (bf16*)alloc((size_t)768 * 3072 * 2);
    // gw1b and svh1b MUST be contiguous: rt1_kernel treats them as one
    // [384, 768] B matrix. 256*768*2 = 393216 B (multiple of 256 -> no pad).
    bf16* gw1b  = (bf16*)alloc((size_t)256 * 768 * 2);
    bf16* svh1b = (bf16*)alloc((size_t)128 * 768 * 2);
    bf16* gw2b  = (bf16*)alloc((size_t)128 * 256 * 2);
    bf16* svh2b = (bf16*)alloc((size_t)128 * 3072 * 2);
    bf16* U1T   = (bf16*)alloc((size_t)3072 * 128 * 2);
    bf16* U2T   = (bf16*)alloc((size_t)768 * 128 * 2);
    float* gsum = (float*)alloc(16 * 256 * 4);
    float* gw   = (float*)alloc(2048 * 4);
    float* b1m  = (float*)alloc(3072 * 4);
    float* b2m  = (float*)alloc(768 * 4);
    float* t1acc  = (float*)alloc((size_t)8192 * 128 * 4);
    float* t2part = (float*)alloc((size_t)4 * 8192 * 128 * 4);

    const dim3 blk(256);

    prep_all<<<11607, blk, 0, stream>>>(x, xb, W1, W1b, W2, W2b,
                                        gate_w1, gw1b, gate_w2, gw2b,
                                        SVH1, svh1b, SVH2, svh2b,
                                        U1, U1T, U2, U2T,
                                        b1, TB1, b2, TB2, b1m, b2m,
                                        gsum);

    // fused router + t1raw (64x64 tiles, 768 balanced blocks)
    rt1_kernel<<<dim3(128, 6), blk, 0, stream>>>(xb, 768, gw1b, 768,
                                                 gate_b1, gsum, t1acc);
    // gw = gsum/512 @ gate_w2^T + gate_b2              [16, 128]
    gw_kernel<<<16, 128, 0, stream>>>(gsum, gw2b, gate_b2, gw);
    // t1 = t1acc * gw -> bf16
    scale_cvt_kernel<<<4096, blk, 0, stream>>>(t1acc, gw, t1buf);

    // h = relu([x|t1] @ [W1|U1T]^T + b1m)              [8192, 3072]
    gemm_bt<<<dim3(64, 24), blk, 0, stream>>>(xb, 768, 768, t1buf, 128, 128,
                                              W1b, 768, U1T, 128,
                                              b1m, 1, hbuf, 3072);

    // t2part[z] = h @ SVH2^T slice (split-K z=4, non-atomic) [4][8192, 128]
    t2_splitk<<<dim3(128, 1, 4), blk, 0, stream>>>(hbuf, 3072, svh2b, 3072, t2part);
    // t2 = (sum_z t2part[z]) * gw -> bf16
    scale_red4_cvt<<<4096, blk, 0, stream>>>(t2part, gw, t2buf);

    // out = [h|t2] @ [W2|U2T]^T + b2m  (fp32 out)      [8192, 768]
    gemm_bt64<<<dim3(128, 6), blk, 0, stream>>>(hbuf, 3072, 3072, t2buf, 128, 128,
                                                W2b, 3072, U2T, 128,
                                                b2m, out, 768);
}